// Round 6
// baseline (685.670 us; speedup 1.0000x reference)
//
#include <hip/hip_runtime.h>

typedef unsigned short u16;
typedef unsigned int u32;
typedef __bf16 bf16_t;
typedef bf16_t bf16x8 __attribute__((ext_vector_type(8)));
typedef float f32x4 __attribute__((ext_vector_type(4)));

#define N_NODES 30000
#define N_EDGES 480000

static __device__ __forceinline__ float b2f(u16 u) {
  return __uint_as_float(((u32)u) << 16);
}
static __device__ __forceinline__ float b2f_lo(u32 w) {
  return __uint_as_float(w << 16);
}
static __device__ __forceinline__ float b2f_hi(u32 w) {
  return __uint_as_float(w & 0xffff0000u);
}
static __device__ __forceinline__ u16 f2b(float f) {
  u32 x = __float_as_uint(f);
  u32 r = (x + 0x7fffu + ((x >> 16) & 1u)) >> 16;
  return (u16)r;
}

// ---------------- dtype sniff: bf16 storage (flag=0) vs f32 storage (flag=1) ----------------
__global__ void sniff(const u16* __restrict__ h, int* __restrict__ flag) {
  int t = threadIdx.x;
  int bad = 0;
#pragma unroll
  for (int i = 0; i < 4; i++) {
    u32 e = ((u32)h[t * 4 + i] >> 7) & 0xFFu;
    if (e >= 0x8Eu) bad = 1;  // impossible magnitude for N(0,1) bf16 data
  }
  int r = __syncthreads_or(bad);
  if (t == 0) *flag = r ? 1 : 0;
}

// ---------------- convert one big array to canonical bf16 ----------------
__global__ __launch_bounds__(256) void conv_arr(const void* __restrict__ src,
                                                u16* __restrict__ dst, int n,
                                                const int* __restrict__ flag) {
  int i = blockIdx.x * 256 + threadIdx.x;
  if (i >= n) return;
  if (*flag) dst[i] = f2b(((const float*)src)[i]);
  else dst[i] = ((const u16*)src)[i];
}

struct ConvDesc { const void* s; u16* d; int n; int off; };
struct ConvTab { ConvDesc e[20]; int total; };

__global__ __launch_bounds__(256) void conv_params(ConvTab tab, const int* __restrict__ flag) {
  int i = blockIdx.x * 256 + threadIdx.x;
  if (i >= tab.total) return;
  int f = *flag;
#pragma unroll 1
  for (int a = 0; a < 20; a++) {
    int j = i - tab.e[a].off;
    if (j >= 0 && j < tab.e[a].n) {
      if (f) tab.e[a].d[j] = f2b(((const float*)tab.e[a].s)[j]);
      else tab.e[a].d[j] = ((const u16*)tab.e[a].s)[j];
      return;
    }
  }
}

// ---------------- CSR build: deg -> off (scan) -> fill ----------------
__global__ __launch_bounds__(256) void deg_count(const int* __restrict__ dst,
                                                 int* __restrict__ deg, int nE) {
  int e = blockIdx.x * 256 + threadIdx.x;
  if (e < nE) atomicAdd(&deg[dst[e]], 1);
}

__global__ __launch_bounds__(256) void scan_off(const int* __restrict__ deg,
                                                int* __restrict__ off, int n) {
  __shared__ int carry;
  __shared__ int wsum[4];
  int t = threadIdx.x, lane = t & 63, wv = t >> 6;
  if (t == 0) { carry = 0; off[0] = 0; }
  __syncthreads();
  for (int base = 0; base < n; base += 256) {
    int v = (base + t < n) ? deg[base + t] : 0;
    int x = v;
#pragma unroll
    for (int d = 1; d < 64; d <<= 1) {
      int y = __shfl_up(x, d, 64);
      if (lane >= d) x += y;
    }
    if (lane == 63) wsum[wv] = x;
    __syncthreads();
    int wadd = 0;
    for (int w = 0; w < wv; w++) wadd += wsum[w];
    int incl = x + wadd + carry;
    if (base + t < n) off[base + t + 1] = incl;
    __syncthreads();
    if (t == 255) carry = incl;
    __syncthreads();
  }
}

__global__ __launch_bounds__(256) void fill_csr(const int* __restrict__ src,
                                                const int* __restrict__ dst,
                                                int* __restrict__ cursor,
                                                int* __restrict__ esrc, int nE) {
  int e = blockIdx.x * 256 + threadIdx.x;
  if (e >= nE) return;
  int p = atomicAdd(&cursor[dst[e]], 1);
  esrc[p] = src[e];
}

// ---------------- CSR max-aggregate: out[n] = max over in-edges of m[src] (bf16, >=0) ----------------
// Unsigned compare on raw u16 == float compare for non-negative bf16.
__global__ __launch_bounds__(256) void agg128(const u16* __restrict__ m,
                                              const int* __restrict__ esrc,
                                              const int* __restrict__ off,
                                              u16* __restrict__ out) {
  int wv = threadIdx.x >> 6, lane = threadIdx.x & 63;
  int n = blockIdx.x * 4 + wv;
  if (n >= N_NODES) return;
  int s0 = off[n], s1 = off[n + 1];
  u32 a0 = 0, a1 = 0;
  int i = s0;
  for (; i + 1 < s1; i += 2) {
    int sa = esrc[i], sb = esrc[i + 1];
    u32 ra = *(const u32*)(m + (size_t)sa * 128 + lane * 2);
    u32 rb = *(const u32*)(m + (size_t)sb * 128 + lane * 2);
    a0 = max(a0, ra & 0xffffu); a1 = max(a1, ra >> 16);
    a0 = max(a0, rb & 0xffffu); a1 = max(a1, rb >> 16);
  }
  if (i < s1) {
    u32 ra = *(const u32*)(m + (size_t)esrc[i] * 128 + lane * 2);
    a0 = max(a0, ra & 0xffffu); a1 = max(a1, ra >> 16);
  }
  *(u32*)(out + (size_t)n * 128 + lane * 2) = a0 | (a1 << 16);
}

__global__ __launch_bounds__(256) void agg256(const u16* __restrict__ m,
                                              const int* __restrict__ esrc,
                                              const int* __restrict__ off,
                                              u16* __restrict__ out) {
  int wv = threadIdx.x >> 6, lane = threadIdx.x & 63;
  int n = blockIdx.x * 4 + wv;
  if (n >= N_NODES) return;
  int s0 = off[n], s1 = off[n + 1];
  u32 a0 = 0, a1 = 0, a2 = 0, a3 = 0;
  int i = s0;
  for (; i + 1 < s1; i += 2) {
    int sa = esrc[i], sb = esrc[i + 1];
    uint2 ra = *(const uint2*)(m + (size_t)sa * 256 + lane * 4);
    uint2 rb = *(const uint2*)(m + (size_t)sb * 256 + lane * 4);
    a0 = max(a0, ra.x & 0xffffu); a1 = max(a1, ra.x >> 16);
    a2 = max(a2, ra.y & 0xffffu); a3 = max(a3, ra.y >> 16);
    a0 = max(a0, rb.x & 0xffffu); a1 = max(a1, rb.x >> 16);
    a2 = max(a2, rb.y & 0xffffu); a3 = max(a3, rb.y >> 16);
  }
  if (i < s1) {
    uint2 ra = *(const uint2*)(m + (size_t)esrc[i] * 256 + lane * 4);
    a0 = max(a0, ra.x & 0xffffu); a1 = max(a1, ra.x >> 16);
    a2 = max(a2, ra.y & 0xffffu); a3 = max(a3, ra.y >> 16);
  }
  uint2 w;
  w.x = a0 | (a1 << 16);
  w.y = a2 | (a3 << 16);
  *(uint2*)(out + (size_t)n * 256 + lane * 4) = w;
}

// ---------------- weight transpose: dst[n*ldo + ko + k] = src[k*Nn + n] ----------------
__global__ void transpose_k(const u16* __restrict__ src, u16* __restrict__ dstp,
                            int K, int nshift, int ldo, int ko) {
  int tid = blockIdx.x * 256 + threadIdx.x;
  int Nn = 1 << nshift;
  int k = tid >> nshift, n = tid & (Nn - 1);
  if (k >= K) return;
  dstp[(size_t)n * ldo + ko + k] = src[(size_t)k * Nn + n];
}

// ---------------- generic MFMA GEMM: C = act(concat(A0,A1) @ Bt^T + bias) ----------------
__global__ __launch_bounds__(256) void gemm_mfma(
    const u16* __restrict__ A0, const u16* __restrict__ A1, int K0, int K1,
    const u16* __restrict__ Bt, const u16* __restrict__ bias, int do_relu,
    u16* __restrict__ C, float* __restrict__ Cf, const int* __restrict__ flag,
    int M, int Nld) {
  __shared__ __align__(16) u16 As[128 * 40];
  __shared__ __align__(16) u16 Bs[128 * 40];
  const int t = threadIdx.x;
  const int lane = t & 63, wv = t >> 6;
  const int wm = wv & 1, wn = wv >> 1;
  const int r = lane & 15, q = lane >> 4;
  const int bm = blockIdx.x, bn = blockIdx.y;
  const int Ktot = K0 + K1;
  const bool usef = (Cf != nullptr) && (*flag != 0);

  f32x4 acc[4][4];
#pragma unroll
  for (int i = 0; i < 4; i++)
#pragma unroll
    for (int j = 0; j < 4; j++) acc[i][j] = (f32x4){0.f, 0.f, 0.f, 0.f};

  for (int kc = 0; kc < Ktot; kc += 32) {
#pragma unroll
    for (int h = 0; h < 2; h++) {
      int idx = t + h * 256;          // 0..511
      int rr = idx >> 2, qq = idx & 3;
      int rowg = bm * 128 + rr;
      uint4 av = make_uint4(0, 0, 0, 0);
      if (rowg < M) {
        const u16* p = (kc < K0) ? (A0 + (size_t)rowg * K0 + kc)
                                 : (A1 + (size_t)rowg * K1 + (kc - K0));
        av = *(const uint4*)(p + qq * 8);
      }
      *(uint4*)&As[rr * 40 + qq * 8] = av;
      int ng = bn * 128 + rr;
      uint4 bv = *(const uint4*)(Bt + (size_t)ng * Ktot + kc + qq * 8);
      *(uint4*)&Bs[rr * 40 + qq * 8] = bv;
    }
    __syncthreads();
    bf16x8 af[4], bfm[4];
#pragma unroll
    for (int mi = 0; mi < 4; mi++)
      af[mi] = *(const bf16x8*)&As[(wm * 64 + mi * 16 + r) * 40 + q * 8];
#pragma unroll
    for (int ni = 0; ni < 4; ni++)
      bfm[ni] = *(const bf16x8*)&Bs[(wn * 64 + ni * 16 + r) * 40 + q * 8];
#pragma unroll
    for (int mi = 0; mi < 4; mi++)
#pragma unroll
      for (int ni = 0; ni < 4; ni++)
        acc[mi][ni] = __builtin_amdgcn_mfma_f32_16x16x32_bf16(af[mi], bfm[ni], acc[mi][ni], 0, 0, 0);
    __syncthreads();
  }

  float bv[4];
#pragma unroll
  for (int ni = 0; ni < 4; ni++)
    bv[ni] = bias ? b2f(bias[bn * 128 + wn * 64 + ni * 16 + r]) : 0.f;
#pragma unroll
  for (int mi = 0; mi < 4; mi++) {
#pragma unroll
    for (int i = 0; i < 4; i++) {
      int rowg = bm * 128 + wm * 64 + mi * 16 + q * 4 + i;
      if (rowg >= M) continue;
#pragma unroll
      for (int ni = 0; ni < 4; ni++) {
        int colg = bn * 128 + wn * 64 + ni * 16 + r;
        float v = acc[mi][ni][i] + bv[ni];
        if (do_relu) v = v > 0.f ? v : 0.f;
        if (usef) Cf[(size_t)rowg * Nld + colg] = v;
        else C[(size_t)rowg * Nld + colg] = f2b(v);
      }
    }
  }
}

// ---------------- node head: node_pred = LN(h1@W + b), smb32 = [softmax | 0-pad] ----------------
__global__ __launch_bounds__(256) void node_head(
    const u16* __restrict__ h1, const u16* __restrict__ W, const u16* __restrict__ b,
    const u16* __restrict__ g, const u16* __restrict__ beta,
    u16* __restrict__ outN, float* __restrict__ outNf, const int* __restrict__ flag,
    u16* __restrict__ smOut) {
  __shared__ float Wl[256 * 5];
  __shared__ float bl[5], gl[5], betal[5];
  int t = threadIdx.x;
#pragma unroll
  for (int c = 0; c < 5; c++) Wl[t * 5 + c] = b2f(W[t * 5 + c]);
  if (t < 5) { bl[t] = b2f(b[t]); gl[t] = b2f(g[t]); betal[t] = b2f(beta[t]); }
  __syncthreads();
  int n = blockIdx.x * 256 + t;
  if (n >= N_NODES) return;
  const bool usef = (*flag != 0);
  float acc[5] = {0.f, 0.f, 0.f, 0.f, 0.f};
  const u16* hp = h1 + (size_t)n * 256;
  for (int k8 = 0; k8 < 32; k8++) {
    uint4 v = *(const uint4*)(hp + k8 * 8);
    u32 wds[4] = {v.x, v.y, v.z, v.w};
#pragma unroll
    for (int h = 0; h < 4; h++) {
      float x0 = b2f_lo(wds[h]), x1 = b2f_hi(wds[h]);
      int k = k8 * 8 + h * 2;
#pragma unroll
      for (int c = 0; c < 5; c++)
        acc[c] += x0 * Wl[k * 5 + c] + x1 * Wl[(k + 1) * 5 + c];
    }
  }
  float x[5], mu = 0.f;
#pragma unroll
  for (int c = 0; c < 5; c++) { x[c] = acc[c] + bl[c]; mu += x[c]; }
  mu *= 0.2f;
  float var = 0.f;
#pragma unroll
  for (int c = 0; c < 5; c++) { float d = x[c] - mu; var += d * d; }
  var *= 0.2f;
  float rstd = rsqrtf(fmaxf(var, 0.f) + 1e-5f);
  float v5[5], mx = -1e30f;
#pragma unroll
  for (int c = 0; c < 5; c++) {
    v5[c] = gl[c] * (x[c] - mu) * rstd + betal[c];
    if (usef) outNf[(size_t)n * 5 + c] = v5[c];
    else outN[(size_t)n * 5 + c] = f2b(v5[c]);
    mx = fmaxf(mx, v5[c]);
  }
  float s = 0.f, ex[5];
#pragma unroll
  for (int c = 0; c < 5; c++) { ex[c] = __expf(v5[c] - mx); s += ex[c]; }
  float inv = 1.f / s;
  u16 row[32];
#pragma unroll
  for (int c = 0; c < 5; c++) row[c] = f2b(ex[c] * inv);
#pragma unroll
  for (int c = 5; c < 32; c++) row[c] = 0;
#pragma unroll
  for (int c = 0; c < 4; c++)
    *(uint4*)(smOut + (size_t)n * 32 + c * 8) = *(const uint4*)&row[c * 8];
}

// ---------------- edge pointwise (pipelined): y = UV[s,0:256]+UV[d,256:512]+ef@Wef ----------------
// -> LN -> relu -> @W2+b2. One wave per edge, 1-deep prefetch of next edge's data.
__global__ __launch_bounds__(256) void edge_pt(
    const u16* __restrict__ UV, const u16* __restrict__ ef,
    const int* __restrict__ src, const int* __restrict__ dst,
    const u16* __restrict__ w1raw,
    const u16* __restrict__ g, const u16* __restrict__ beta,
    const u16* __restrict__ w2, const u16* __restrict__ b2,
    u16* __restrict__ outE, float* __restrict__ outEf, const int* __restrict__ flag) {
  const int t = threadIdx.x;
  const int lane = t & 63, wv = t >> 6;
  const int c0 = lane * 4;
  // per-lane constants in registers
  float wef[6][4], gl[4], bl[4], w20[4], w21[4];
#pragma unroll
  for (int k = 0; k < 6; k++) {
    u32 wa = *(const u32*)(w1raw + (size_t)(261 + k) * 256 + c0);
    u32 wb = *(const u32*)(w1raw + (size_t)(261 + k) * 256 + c0 + 2);
    wef[k][0] = b2f_lo(wa); wef[k][1] = b2f_hi(wa);
    wef[k][2] = b2f_lo(wb); wef[k][3] = b2f_hi(wb);
  }
#pragma unroll
  for (int j = 0; j < 4; j++) {
    gl[j] = b2f(g[c0 + j]); bl[j] = b2f(beta[c0 + j]);
    w20[j] = b2f(w2[(c0 + j) * 2]); w21[j] = b2f(w2[(c0 + j) * 2 + 1]);
  }
  const float b20 = b2f(b2[0]), b21 = b2f(b2[1]);
  const bool usef = (*flag != 0);
  const int stride = gridDim.x * 4;  // 7500: divides N_EDGES exactly (64 iters/wave)
  int e = blockIdx.x * 4 + wv;
  // prologue: load edge e's data
  int s0 = src[e], d0 = dst[e];
  uint2 uu = *(const uint2*)(UV + (size_t)s0 * 512 + c0);
  uint2 vv = *(const uint2*)(UV + (size_t)d0 * 512 + 256 + c0);
  u32 f0 = *(const u32*)(ef + (size_t)e * 6);
  u32 f1 = *(const u32*)(ef + (size_t)e * 6 + 2);
  u32 f2 = *(const u32*)(ef + (size_t)e * 6 + 4);
  while (e < N_EDGES) {
    int en = e + stride;
    uint2 uun = uu, vvn = vv;
    u32 g0 = f0, g1 = f1, g2 = f2;
    if (en < N_EDGES) {  // wave-uniform branch: prefetch next edge
      int sn = src[en], dn = dst[en];
      uun = *(const uint2*)(UV + (size_t)sn * 512 + c0);
      vvn = *(const uint2*)(UV + (size_t)dn * 512 + 256 + c0);
      g0 = *(const u32*)(ef + (size_t)en * 6);
      g1 = *(const u32*)(ef + (size_t)en * 6 + 2);
      g2 = *(const u32*)(ef + (size_t)en * 6 + 4);
    }
    // compute current edge
    float xe[6] = {b2f_lo(f0), b2f_hi(f0), b2f_lo(f1), b2f_hi(f1), b2f_lo(f2), b2f_hi(f2)};
    float y[4];
    y[0] = b2f_lo(uu.x) + b2f_lo(vv.x);
    y[1] = b2f_hi(uu.x) + b2f_hi(vv.x);
    y[2] = b2f_lo(uu.y) + b2f_lo(vv.y);
    y[3] = b2f_hi(uu.y) + b2f_hi(vv.y);
#pragma unroll
    for (int k = 0; k < 6; k++)
#pragma unroll
      for (int j = 0; j < 4; j++) y[j] += xe[k] * wef[k][j];
    float ps = y[0] + y[1] + y[2] + y[3];
    float pq = y[0] * y[0] + y[1] * y[1] + y[2] * y[2] + y[3] * y[3];
#pragma unroll
    for (int m = 1; m < 64; m <<= 1) {
      ps += __shfl_xor(ps, m, 64);
      pq += __shfl_xor(pq, m, 64);
    }
    float mean = ps * (1.f / 256.f);
    float var = pq * (1.f / 256.f) - mean * mean;
    float rstd = rsqrtf(fmaxf(var, 0.f) + 1e-5f);
    float p0 = 0.f, p1 = 0.f;
#pragma unroll
    for (int j = 0; j < 4; j++) {
      float yy = (y[j] - mean) * rstd * gl[j] + bl[j];
      yy = fmaxf(yy, 0.f);
      p0 += yy * w20[j]; p1 += yy * w21[j];
    }
#pragma unroll
    for (int m = 1; m < 64; m <<= 1) {
      p0 += __shfl_xor(p0, m, 64);
      p1 += __shfl_xor(p1, m, 64);
    }
    if (lane == 0) {
      float v0 = p0 + b20, v1 = p1 + b21;
      if (usef) {
        *(float2*)(outEf + (size_t)e * 2) = make_float2(v0, v1);
      } else {
        u32 pk = (u32)f2b(v0) | ((u32)f2b(v1) << 16);
        *(u32*)(outE + (size_t)e * 2) = pk;
      }
    }
    uu = uun; vv = vvn; f0 = g0; f1 = g1; f2 = g2;
    e = en;
  }
}

extern "C" void kernel_launch(void* const* d_in, const int* in_sizes, int n_in,
                              void* d_out, int out_size, void* d_ws, size_t ws_size,
                              hipStream_t stream) {
  char* wp = (char*)d_ws;
  auto alloc = [&](size_t bytes) -> char* {
    char* p = wp; wp += (bytes + 255) & ~(size_t)255; return p;
  };
  int* flag       = (int*)alloc(256);
  // canonical bf16 copies of all float inputs
  u16* c_h        = (u16*)alloc((size_t)N_NODES * 128 * 2);
  u16* c_ef       = (u16*)alloc((size_t)N_EDGES * 6 * 2);
  static const int pidx[20] = {4,5,6,7,8, 9,10,11,12, 13,14,15,16,17,18, 19,20,21,22,23};
  static const int pn[20]   = {16384,128,32768,256,32768, 1280,5,5,5,
                               135168,256,256,256,512,2, 65536,256,32768,128,32768};
  u16* cp[20];
  for (int a = 0; a < 20; a++) cp[a] = (u16*)alloc((size_t)pn[a] * 2);

  u16* wt_encpool = (u16*)alloc(128 * 128 * 2);
  u16* wt_enc     = (u16*)alloc(256 * 256 * 2);
  u16* wt_decpool = (u16*)alloc(256 * 256 * 2);
  u16* wt_dec     = (u16*)alloc(128 * 512 * 2);
  u16* wt_UV      = (u16*)alloc(512 * 288 * 2);
  u16* b512       = (u16*)alloc(512 * 2);
  // m_buf and aggb are contiguous (each 15,360,000 B, 256-aligned) => combined
  // [N_NODES][512] UV buffer during the edge phase.
  u16* m_buf      = (u16*)alloc((size_t)N_NODES * 256 * 2);
  u16* aggb       = (u16*)alloc((size_t)N_NODES * 256 * 2);
  u16* UVbuf      = m_buf;
  u16* h1b        = (u16*)alloc((size_t)N_NODES * 256 * 2);
  u16* smb32      = (u16*)alloc((size_t)N_NODES * 32 * 2);
  // CSR
  int* deg        = (int*)alloc((size_t)N_NODES * 4);
  int* off        = (int*)alloc((size_t)(N_NODES + 1) * 4);
  int* cursor     = (int*)alloc((size_t)N_NODES * 4);
  int* esrc       = (int*)alloc((size_t)N_EDGES * 4);

  const int* src = (const int*)d_in[2];
  const int* dst = (const int*)d_in[3];

  u16* outN = (u16*)d_out;
  u16* outE = outN + (size_t)N_NODES * 5;
  u16* outH = outN + 1110000;
  float* outNf = (float*)d_out;
  float* outEf = outNf + (size_t)N_NODES * 5;
  float* outHf = outNf + 1110000;

  // --- dtype sniff + input conversion ---
  sniff<<<1, 256, 0, stream>>>((const u16*)d_in[0], flag);
  conv_arr<<<15000, 256, 0, stream>>>(d_in[0], c_h, N_NODES * 128, flag);
  conv_arr<<<11250, 256, 0, stream>>>(d_in[1], c_ef, N_EDGES * 6, flag);
  ConvTab tab;
  int off_a = 0;
  for (int a = 0; a < 20; a++) {
    tab.e[a].s = d_in[pidx[a]]; tab.e[a].d = cp[a]; tab.e[a].n = pn[a]; tab.e[a].off = off_a;
    off_a += pn[a];
  }
  tab.total = off_a;
  conv_params<<<(off_a + 255) / 256, 256, 0, stream>>>(tab, flag);

  const u16 *enc_Wpool = cp[0], *enc_bpool = cp[1], *enc_Wself = cp[2], *enc_bself = cp[3],
            *enc_Wneigh = cp[4], *np_W = cp[5], *np_b = cp[6], *np_g = cp[7], *np_beta = cp[8],
            *ep_W1 = cp[9], *ep_b1 = cp[10], *ep_g = cp[11], *ep_beta = cp[12],
            *ep_W2 = cp[13], *ep_b2 = cp[14], *dec_Wpool = cp[15], *dec_bpool = cp[16],
            *dec_Wself = cp[17], *dec_bself = cp[18], *dec_Wneigh = cp[19];

  // --- CSR build (shared by both aggregations) ---
  hipMemsetAsync(deg, 0, (size_t)N_NODES * 4, stream);
  deg_count<<<1875, 256, 0, stream>>>(dst, deg, N_EDGES);
  scan_off<<<1, 256, 0, stream>>>(deg, off, N_NODES);
  hipMemcpyAsync(cursor, off, (size_t)N_NODES * 4, hipMemcpyDeviceToDevice, stream);
  fill_csr<<<1875, 256, 0, stream>>>(src, dst, cursor, esrc, N_EDGES);

  // --- weight prep ---
  transpose_k<<<64, 256, 0, stream>>>(enc_Wpool, wt_encpool, 128, 7, 128, 0);
  transpose_k<<<128, 256, 0, stream>>>(enc_Wself, wt_enc, 128, 8, 256, 0);
  transpose_k<<<128, 256, 0, stream>>>(enc_Wneigh, wt_enc, 128, 8, 256, 128);
  transpose_k<<<256, 256, 0, stream>>>(dec_Wpool, wt_decpool, 256, 8, 256, 0);
  transpose_k<<<128, 256, 0, stream>>>(dec_Wself, wt_dec, 256, 7, 512, 0);
  transpose_k<<<128, 256, 0, stream>>>(dec_Wneigh, wt_dec, 256, 7, 512, 256);
  // wt_UV rows 0..255 = U cols (W1 rows 0..255 | 256..260 | pad to 288);
  //        rows 256..511 = V cols (W1 rows 267..522 | 523..527 | pad).
  hipMemsetAsync(wt_UV, 0, 512 * 288 * 2, stream);
  transpose_k<<<256, 256, 0, stream>>>(ep_W1, wt_UV, 256, 8, 288, 0);
  transpose_k<<<5, 256, 0, stream>>>(ep_W1 + 256 * 256, wt_UV, 5, 8, 288, 256);
  transpose_k<<<256, 256, 0, stream>>>(ep_W1 + 267 * 256, wt_UV + 256 * 288, 256, 8, 288, 0);
  transpose_k<<<5, 256, 0, stream>>>(ep_W1 + 523 * 256, wt_UV + 256 * 288, 5, 8, 288, 256);
  // b512 = [ep_b1 | zeros]
  hipMemsetAsync(b512, 0, 512 * 2, stream);
  hipMemcpyAsync(b512, ep_b1, 256 * 2, hipMemcpyDeviceToDevice, stream);

  // --- encoder ---
  gemm_mfma<<<dim3(235, 1), 256, 0, stream>>>(c_h, nullptr, 128, 0, wt_encpool,
                                              enc_bpool, 1, m_buf, nullptr, flag, N_NODES, 128);
  agg128<<<7500, 256, 0, stream>>>(m_buf, esrc, off, aggb);
  gemm_mfma<<<dim3(235, 2), 256, 0, stream>>>(c_h, aggb, 128, 128, wt_enc,
                                              enc_bself, 1, h1b, nullptr, flag, N_NODES, 256);
  // --- node head (also emits padded softmax rows) ---
  node_head<<<118, 256, 0, stream>>>(h1b, np_W, np_b, np_g, np_beta, outN, outNf, flag, smb32);
  // --- edge head: fused UV precompute (one N=512 GEMM), then pipelined pointwise kernel ---
  gemm_mfma<<<dim3(235, 4), 256, 0, stream>>>(h1b, smb32, 256, 32, wt_UV,
                                              b512, 0, UVbuf, nullptr, flag, N_NODES, 512);
  edge_pt<<<1875, 256, 0, stream>>>(UVbuf, c_ef, src, dst, ep_W1,
                                    ep_g, ep_beta, ep_W2, ep_b2, outE, outEf, flag);
  // --- decoder (m_buf/aggb reusable again) ---
  gemm_mfma<<<dim3(235, 2), 256, 0, stream>>>(h1b, nullptr, 256, 0, wt_decpool,
                                              dec_bpool, 1, m_buf, nullptr, flag, N_NODES, 256);
  agg256<<<7500, 256, 0, stream>>>(m_buf, esrc, off, aggb);
  gemm_mfma<<<dim3(235, 1), 256, 0, stream>>>(h1b, aggb, 256, 256, wt_dec,
                                              dec_bself, 1, outH, outHf, flag, N_NODES, 128);
}

// Round 7
// 603.043 us; speedup vs baseline: 1.1370x; 1.1370x over previous
//
#include <hip/hip_runtime.h>

typedef unsigned short u16;
typedef unsigned int u32;
typedef __bf16 bf16_t;
typedef bf16_t bf16x8 __attribute__((ext_vector_type(8)));
typedef float f32x4 __attribute__((ext_vector_type(4)));

#define N_NODES 30000
#define N_EDGES 480000

static __device__ __forceinline__ float b2f(u16 u) {
  return __uint_as_float(((u32)u) << 16);
}
static __device__ __forceinline__ float b2f_lo(u32 w) {
  return __uint_as_float(w << 16);
}
static __device__ __forceinline__ float b2f_hi(u32 w) {
  return __uint_as_float(w & 0xffff0000u);
}
static __device__ __forceinline__ u16 f2b(float f) {
  u32 x = __float_as_uint(f);
  u32 r = (x + 0x7fffu + ((x >> 16) & 1u)) >> 16;
  return (u16)r;
}

// ---------------- dtype sniff: bf16 storage (flag=0) vs f32 storage (flag=1) ----------------
__global__ void sniff(const u16* __restrict__ h, int* __restrict__ flag) {
  int t = threadIdx.x;
  int bad = 0;
#pragma unroll
  for (int i = 0; i < 4; i++) {
    u32 e = ((u32)h[t * 4 + i] >> 7) & 0xFFu;
    if (e >= 0x8Eu) bad = 1;  // impossible magnitude for N(0,1) bf16 data
  }
  int r = __syncthreads_or(bad);
  if (t == 0) *flag = r ? 1 : 0;
}

// ---------------- convert one big array to canonical bf16 ----------------
__global__ __launch_bounds__(256) void conv_arr(const void* __restrict__ src,
                                                u16* __restrict__ dst, int n,
                                                const int* __restrict__ flag) {
  int i = blockIdx.x * 256 + threadIdx.x;
  if (i >= n) return;
  if (*flag) dst[i] = f2b(((const float*)src)[i]);
  else dst[i] = ((const u16*)src)[i];
}

struct ConvDesc { const void* s; u16* d; int n; int off; };
struct ConvTab { ConvDesc e[20]; int total; };

__global__ __launch_bounds__(256) void conv_params(ConvTab tab, const int* __restrict__ flag) {
  int i = blockIdx.x * 256 + threadIdx.x;
  if (i >= tab.total) return;
  int f = *flag;
#pragma unroll 1
  for (int a = 0; a < 20; a++) {
    int j = i - tab.e[a].off;
    if (j >= 0 && j < tab.e[a].n) {
      if (f) tab.e[a].d[j] = f2b(((const float*)tab.e[a].s)[j]);
      else tab.e[a].d[j] = ((const u16*)tab.e[a].s)[j];
      return;
    }
  }
}

// ---------------- CSR build: deg -> off (scan) -> fill ----------------
__global__ __launch_bounds__(256) void deg_count(const int* __restrict__ dst,
                                                 int* __restrict__ deg, int nE) {
  int e = blockIdx.x * 256 + threadIdx.x;
  if (e < nE) atomicAdd(&deg[dst[e]], 1);
}

__global__ __launch_bounds__(256) void scan_off(const int* __restrict__ deg,
                                                int* __restrict__ off, int n) {
  __shared__ int carry;
  __shared__ int wsum[4];
  int t = threadIdx.x, lane = t & 63, wv = t >> 6;
  if (t == 0) { carry = 0; off[0] = 0; }
  __syncthreads();
  for (int base = 0; base < n; base += 256) {
    int v = (base + t < n) ? deg[base + t] : 0;
    int x = v;
#pragma unroll
    for (int d = 1; d < 64; d <<= 1) {
      int y = __shfl_up(x, d, 64);
      if (lane >= d) x += y;
    }
    if (lane == 63) wsum[wv] = x;
    __syncthreads();
    int wadd = 0;
    for (int w = 0; w < wv; w++) wadd += wsum[w];
    int incl = x + wadd + carry;
    if (base + t < n) off[base + t + 1] = incl;
    __syncthreads();
    if (t == 255) carry = incl;
    __syncthreads();
  }
}

__global__ __launch_bounds__(256) void fill_csr(const int* __restrict__ src,
                                                const int* __restrict__ dst,
                                                int* __restrict__ cursor,
                                                int* __restrict__ esrc, int nE) {
  int e = blockIdx.x * 256 + threadIdx.x;
  if (e >= nE) return;
  int p = atomicAdd(&cursor[dst[e]], 1);
  esrc[p] = src[e];
}

// ---------------- CSR max-aggregate: out[n] = max over in-edges of m[src] (bf16, >=0) ----------------
__global__ __launch_bounds__(256) void agg128(const u16* __restrict__ m,
                                              const int* __restrict__ esrc,
                                              const int* __restrict__ off,
                                              u16* __restrict__ out) {
  int wv = threadIdx.x >> 6, lane = threadIdx.x & 63;
  int n = blockIdx.x * 4 + wv;
  if (n >= N_NODES) return;
  int s0 = off[n], s1 = off[n + 1];
  u32 a0 = 0, a1 = 0;
  int i = s0;
  for (; i + 1 < s1; i += 2) {
    int sa = esrc[i], sb = esrc[i + 1];
    u32 ra = *(const u32*)(m + (size_t)sa * 128 + lane * 2);
    u32 rb = *(const u32*)(m + (size_t)sb * 128 + lane * 2);
    a0 = max(a0, ra & 0xffffu); a1 = max(a1, ra >> 16);
    a0 = max(a0, rb & 0xffffu); a1 = max(a1, rb >> 16);
  }
  if (i < s1) {
    u32 ra = *(const u32*)(m + (size_t)esrc[i] * 128 + lane * 2);
    a0 = max(a0, ra & 0xffffu); a1 = max(a1, ra >> 16);
  }
  *(u32*)(out + (size_t)n * 128 + lane * 2) = a0 | (a1 << 16);
}

__global__ __launch_bounds__(256) void agg256(const u16* __restrict__ m,
                                              const int* __restrict__ esrc,
                                              const int* __restrict__ off,
                                              u16* __restrict__ out) {
  int wv = threadIdx.x >> 6, lane = threadIdx.x & 63;
  int n = blockIdx.x * 4 + wv;
  if (n >= N_NODES) return;
  int s0 = off[n], s1 = off[n + 1];
  u32 a0 = 0, a1 = 0, a2 = 0, a3 = 0;
  int i = s0;
  for (; i + 1 < s1; i += 2) {
    int sa = esrc[i], sb = esrc[i + 1];
    uint2 ra = *(const uint2*)(m + (size_t)sa * 256 + lane * 4);
    uint2 rb = *(const uint2*)(m + (size_t)sb * 256 + lane * 4);
    a0 = max(a0, ra.x & 0xffffu); a1 = max(a1, ra.x >> 16);
    a2 = max(a2, ra.y & 0xffffu); a3 = max(a3, ra.y >> 16);
    a0 = max(a0, rb.x & 0xffffu); a1 = max(a1, rb.x >> 16);
    a2 = max(a2, rb.y & 0xffffu); a3 = max(a3, rb.y >> 16);
  }
  if (i < s1) {
    uint2 ra = *(const uint2*)(m + (size_t)esrc[i] * 256 + lane * 4);
    a0 = max(a0, ra.x & 0xffffu); a1 = max(a1, ra.x >> 16);
    a2 = max(a2, ra.y & 0xffffu); a3 = max(a3, ra.y >> 16);
  }
  uint2 w;
  w.x = a0 | (a1 << 16);
  w.y = a2 | (a3 << 16);
  *(uint2*)(out + (size_t)n * 256 + lane * 4) = w;
}

// ---------------- weight transpose: dst[n*ldo + ko + k] = src[k*Nn + n] ----------------
__global__ void transpose_k(const u16* __restrict__ src, u16* __restrict__ dstp,
                            int K, int nshift, int ldo, int ko) {
  int tid = blockIdx.x * 256 + threadIdx.x;
  int Nn = 1 << nshift;
  int k = tid >> nshift, n = tid & (Nn - 1);
  if (k >= K) return;
  dstp[(size_t)n * ldo + ko + k] = src[(size_t)k * Nn + n];
}

// ---------------- generic MFMA GEMM: C = act(concat(A0,A1) @ Bt^T + bias) ----------------
__global__ __launch_bounds__(256) void gemm_mfma(
    const u16* __restrict__ A0, const u16* __restrict__ A1, int K0, int K1,
    const u16* __restrict__ Bt, const u16* __restrict__ bias, int do_relu,
    u16* __restrict__ C, float* __restrict__ Cf, const int* __restrict__ flag,
    int M, int Nld) {
  __shared__ __align__(16) u16 As[128 * 40];
  __shared__ __align__(16) u16 Bs[128 * 40];
  const int t = threadIdx.x;
  const int lane = t & 63, wv = t >> 6;
  const int wm = wv & 1, wn = wv >> 1;
  const int r = lane & 15, q = lane >> 4;
  const int bm = blockIdx.x, bn = blockIdx.y;
  const int Ktot = K0 + K1;
  const bool usef = (Cf != nullptr) && (*flag != 0);

  f32x4 acc[4][4];
#pragma unroll
  for (int i = 0; i < 4; i++)
#pragma unroll
    for (int j = 0; j < 4; j++) acc[i][j] = (f32x4){0.f, 0.f, 0.f, 0.f};

  for (int kc = 0; kc < Ktot; kc += 32) {
#pragma unroll
    for (int h = 0; h < 2; h++) {
      int idx = t + h * 256;          // 0..511
      int rr = idx >> 2, qq = idx & 3;
      int rowg = bm * 128 + rr;
      uint4 av = make_uint4(0, 0, 0, 0);
      if (rowg < M) {
        const u16* p = (kc < K0) ? (A0 + (size_t)rowg * K0 + kc)
                                 : (A1 + (size_t)rowg * K1 + (kc - K0));
        av = *(const uint4*)(p + qq * 8);
      }
      *(uint4*)&As[rr * 40 + qq * 8] = av;
      int ng = bn * 128 + rr;
      uint4 bv = *(const uint4*)(Bt + (size_t)ng * Ktot + kc + qq * 8);
      *(uint4*)&Bs[rr * 40 + qq * 8] = bv;
    }
    __syncthreads();
    bf16x8 af[4], bfm[4];
#pragma unroll
    for (int mi = 0; mi < 4; mi++)
      af[mi] = *(const bf16x8*)&As[(wm * 64 + mi * 16 + r) * 40 + q * 8];
#pragma unroll
    for (int ni = 0; ni < 4; ni++)
      bfm[ni] = *(const bf16x8*)&Bs[(wn * 64 + ni * 16 + r) * 40 + q * 8];
#pragma unroll
    for (int mi = 0; mi < 4; mi++)
#pragma unroll
      for (int ni = 0; ni < 4; ni++)
        acc[mi][ni] = __builtin_amdgcn_mfma_f32_16x16x32_bf16(af[mi], bfm[ni], acc[mi][ni], 0, 0, 0);
    __syncthreads();
  }

  float bv[4];
#pragma unroll
  for (int ni = 0; ni < 4; ni++)
    bv[ni] = bias ? b2f(bias[bn * 128 + wn * 64 + ni * 16 + r]) : 0.f;
#pragma unroll
  for (int mi = 0; mi < 4; mi++) {
#pragma unroll
    for (int i = 0; i < 4; i++) {
      int rowg = bm * 128 + wm * 64 + mi * 16 + q * 4 + i;
      if (rowg >= M) continue;
#pragma unroll
      for (int ni = 0; ni < 4; ni++) {
        int colg = bn * 128 + wn * 64 + ni * 16 + r;
        float v = acc[mi][ni][i] + bv[ni];
        if (do_relu) v = v > 0.f ? v : 0.f;
        if (usef) Cf[(size_t)rowg * Nld + colg] = v;
        else C[(size_t)rowg * Nld + colg] = f2b(v);
      }
    }
  }
}

// ---------------- node head: node_pred = LN(h1@W + b), smb32 = [softmax | 0-pad] ----------------
__global__ __launch_bounds__(256) void node_head(
    const u16* __restrict__ h1, const u16* __restrict__ W, const u16* __restrict__ b,
    const u16* __restrict__ g, const u16* __restrict__ beta,
    u16* __restrict__ outN, float* __restrict__ outNf, const int* __restrict__ flag,
    u16* __restrict__ smOut) {
  __shared__ float Wl[256 * 5];
  __shared__ float bl[5], gl[5], betal[5];
  int t = threadIdx.x;
#pragma unroll
  for (int c = 0; c < 5; c++) Wl[t * 5 + c] = b2f(W[t * 5 + c]);
  if (t < 5) { bl[t] = b2f(b[t]); gl[t] = b2f(g[t]); betal[t] = b2f(beta[t]); }
  __syncthreads();
  int n = blockIdx.x * 256 + t;
  if (n >= N_NODES) return;
  const bool usef = (*flag != 0);
  float acc[5] = {0.f, 0.f, 0.f, 0.f, 0.f};
  const u16* hp = h1 + (size_t)n * 256;
  for (int k8 = 0; k8 < 32; k8++) {
    uint4 v = *(const uint4*)(hp + k8 * 8);
    u32 wds[4] = {v.x, v.y, v.z, v.w};
#pragma unroll
    for (int h = 0; h < 4; h++) {
      float x0 = b2f_lo(wds[h]), x1 = b2f_hi(wds[h]);
      int k = k8 * 8 + h * 2;
#pragma unroll
      for (int c = 0; c < 5; c++)
        acc[c] += x0 * Wl[k * 5 + c] + x1 * Wl[(k + 1) * 5 + c];
    }
  }
  float x[5], mu = 0.f;
#pragma unroll
  for (int c = 0; c < 5; c++) { x[c] = acc[c] + bl[c]; mu += x[c]; }
  mu *= 0.2f;
  float var = 0.f;
#pragma unroll
  for (int c = 0; c < 5; c++) { float d = x[c] - mu; var += d * d; }
  var *= 0.2f;
  float rstd = rsqrtf(fmaxf(var, 0.f) + 1e-5f);
  float v5[5], mx = -1e30f;
#pragma unroll
  for (int c = 0; c < 5; c++) {
    v5[c] = gl[c] * (x[c] - mu) * rstd + betal[c];
    if (usef) outNf[(size_t)n * 5 + c] = v5[c];
    else outN[(size_t)n * 5 + c] = f2b(v5[c]);
    mx = fmaxf(mx, v5[c]);
  }
  float s = 0.f, ex[5];
#pragma unroll
  for (int c = 0; c < 5; c++) { ex[c] = __expf(v5[c] - mx); s += ex[c]; }
  float inv = 1.f / s;
  u16 row[32];
#pragma unroll
  for (int c = 0; c < 5; c++) row[c] = f2b(ex[c] * inv);
#pragma unroll
  for (int c = 5; c < 32; c++) row[c] = 0;
#pragma unroll
  for (int c = 0; c < 4; c++)
    *(uint4*)(smOut + (size_t)n * 32 + c * 8) = *(const uint4*)&row[c * 8];
}

// ---------------- row sums of UV: Srow[n] = (sum U[n][0:256], sum V[n][256:512]) ----------------
__global__ __launch_bounds__(256) void rowsum_uv(const u16* __restrict__ UV,
                                                 float2* __restrict__ Srow) {
  int wv = threadIdx.x >> 6, lane = threadIdx.x & 63;
  int n = blockIdx.x * 4 + wv;
  if (n >= N_NODES) return;
  uint4 v = *(const uint4*)(UV + (size_t)n * 512 + lane * 8);
  float s = b2f_lo(v.x) + b2f_hi(v.x) + b2f_lo(v.y) + b2f_hi(v.y) +
            b2f_lo(v.z) + b2f_hi(v.z) + b2f_lo(v.w) + b2f_hi(v.w);
#pragma unroll
  for (int m = 1; m < 32; m <<= 1) s += __shfl_xor(s, m, 64);
  if (lane == 0) Srow[n].x = s;    // U half (cols 0..255, lanes 0-31)
  if (lane == 32) Srow[n].y = s;   // V half (cols 256..511, lanes 32-63)
}

// ---------------- wef column sums: swsum[k] = sum_c W1[261+k][c] ----------------
__global__ void wefsum(const u16* __restrict__ w1raw, float* __restrict__ swsum) {
  int k = threadIdx.x >> 6, lane = threadIdx.x & 63;  // 6 waves
  if (k >= 6) return;
  uint2 v = *(const uint2*)(w1raw + (size_t)(261 + k) * 256 + lane * 4);
  float s = b2f_lo(v.x) + b2f_hi(v.x) + b2f_lo(v.y) + b2f_hi(v.y);
#pragma unroll
  for (int m = 1; m < 64; m <<= 1) s += __shfl_xor(s, m, 64);
  if (lane == 0) swsum[k] = s;
}

// ---------------- edge pointwise v3: pair-per-iteration, reduced shuffle trees ----------------
// y = UV[s,0:256]+UV[d,256:512]+ef@Wef; mean from precomputed row sums; LN->relu->W2.
__global__ __launch_bounds__(256) void edge_pt(
    const u16* __restrict__ UV, const float2* __restrict__ Srow,
    const float* __restrict__ swsum, const u16* __restrict__ ef,
    const int* __restrict__ src, const int* __restrict__ dst,
    const u16* __restrict__ w1raw,
    const u16* __restrict__ g, const u16* __restrict__ beta,
    const u16* __restrict__ w2, const u16* __restrict__ b2,
    u16* __restrict__ outE, float* __restrict__ outEf, const int* __restrict__ flag) {
  const int t = threadIdx.x;
  const int lane = t & 63, wv = t >> 6;
  const int c0 = lane * 4;
  const int grp = (lane >> 4) & 3;  // 16-lane group id
  float wef[6][4], gl[4], bl[4], w20[4], w21[4];
#pragma unroll
  for (int k = 0; k < 6; k++) {
    u32 wa = *(const u32*)(w1raw + (size_t)(261 + k) * 256 + c0);
    u32 wb = *(const u32*)(w1raw + (size_t)(261 + k) * 256 + c0 + 2);
    wef[k][0] = b2f_lo(wa); wef[k][1] = b2f_hi(wa);
    wef[k][2] = b2f_lo(wb); wef[k][3] = b2f_hi(wb);
  }
#pragma unroll
  for (int j = 0; j < 4; j++) {
    gl[j] = b2f(g[c0 + j]); bl[j] = b2f(beta[c0 + j]);
    w20[j] = b2f(w2[(c0 + j) * 2]); w21[j] = b2f(w2[(c0 + j) * 2 + 1]);
  }
  float sw[6];
#pragma unroll
  for (int k = 0; k < 6; k++) sw[k] = swsum[k];
  const float b20 = b2f(b2[0]), b21 = b2f(b2[1]);
  const float bsel = (grp & 1) ? b21 : b20;
  const bool usef = (*flag != 0);

  const int pbase = (blockIdx.x * 4 + wv) * 32;  // 1875*4*32 pairs = 240000
  int sa = src[pbase * 2], da = dst[pbase * 2];
  int sb = src[pbase * 2 + 1], db = dst[pbase * 2 + 1];
#pragma unroll 1
  for (int it = 0; it < 32; ++it) {
    const int e = (pbase + it) * 2;
    int sac = sa, dac = da, sbc = sb, dbc = db;
    if (it + 1 < 32) {
      sa = src[e + 2]; da = dst[e + 2]; sb = src[e + 3]; db = dst[e + 3];
    }
    uint2 ua = *(const uint2*)(UV + (size_t)sac * 512 + c0);
    uint2 va = *(const uint2*)(UV + (size_t)dac * 512 + 256 + c0);
    uint2 ub = *(const uint2*)(UV + (size_t)sbc * 512 + c0);
    uint2 vb = *(const uint2*)(UV + (size_t)dbc * 512 + 256 + c0);
    float2 sra = Srow[sac], srda = Srow[dac];
    float2 srb = Srow[sbc], srdb = Srow[dbc];
    const u32* efp = (const u32*)(ef + (size_t)e * 6);
    u32 f0 = efp[0], f1 = efp[1], f2 = efp[2], f3 = efp[3], f4 = efp[4], f5 = efp[5];
    float xa[6] = {b2f_lo(f0), b2f_hi(f0), b2f_lo(f1), b2f_hi(f1), b2f_lo(f2), b2f_hi(f2)};
    float xb[6] = {b2f_lo(f3), b2f_hi(f3), b2f_lo(f4), b2f_hi(f4), b2f_lo(f5), b2f_hi(f5)};

    float ma = sra.x + srda.y, mb = srb.x + srdb.y;
#pragma unroll
    for (int k = 0; k < 6; k++) { ma += xa[k] * sw[k]; mb += xb[k] * sw[k]; }
    ma *= (1.f / 256.f); mb *= (1.f / 256.f);

    float ya[4], yb[4];
    ya[0] = b2f_lo(ua.x) + b2f_lo(va.x); yb[0] = b2f_lo(ub.x) + b2f_lo(vb.x);
    ya[1] = b2f_hi(ua.x) + b2f_hi(va.x); yb[1] = b2f_hi(ub.x) + b2f_hi(vb.x);
    ya[2] = b2f_lo(ua.y) + b2f_lo(va.y); yb[2] = b2f_lo(ub.y) + b2f_lo(vb.y);
    ya[3] = b2f_hi(ua.y) + b2f_hi(va.y); yb[3] = b2f_hi(ub.y) + b2f_hi(vb.y);
#pragma unroll
    for (int k = 0; k < 6; k++)
#pragma unroll
      for (int j = 0; j < 4; j++) {
        ya[j] += xa[k] * wef[k][j];
        yb[j] += xb[k] * wef[k][j];
      }
    float pqa = ya[0] * ya[0] + ya[1] * ya[1] + ya[2] * ya[2] + ya[3] * ya[3];
    float pqb = yb[0] * yb[0] + yb[1] * yb[1] + yb[2] * yb[2] + yb[3] * yb[3];
    // reduction 1: both sumsq in one half-tree (8 shuffles)
    pqa += __shfl_xor(pqa, 32, 64);
    pqb += __shfl_xor(pqb, 32, 64);
    float z = (lane < 32) ? pqa : pqb;
#pragma unroll
    for (int m = 16; m >= 1; m >>= 1) z += __shfl_xor(z, m, 64);
    float zz = __shfl_xor(z, 32, 64);
    float pqa_t = (lane < 32) ? z : zz;
    float pqb_t = (lane < 32) ? zz : z;
    float rsa = rsqrtf(fmaxf(pqa_t * (1.f / 256.f) - ma * ma, 0.f) + 1e-5f);
    float rsb = rsqrtf(fmaxf(pqb_t * (1.f / 256.f) - mb * mb, 0.f) + 1e-5f);
    // normalize + relu + W2 partials
    float p0a = 0.f, p1a = 0.f, p0b = 0.f, p1b = 0.f;
#pragma unroll
    for (int j = 0; j < 4; j++) {
      float na = fmaxf((ya[j] - ma) * rsa * gl[j] + bl[j], 0.f);
      float nb = fmaxf((yb[j] - mb) * rsb * gl[j] + bl[j], 0.f);
      p0a += na * w20[j]; p1a += na * w21[j];
      p0b += nb * w20[j]; p1b += nb * w21[j];
    }
    // reduction 2: four values via group-16 packing (12 shuffles)
    p0a += __shfl_xor(p0a, 32, 64); p1a += __shfl_xor(p1a, 32, 64);
    p0b += __shfl_xor(p0b, 32, 64); p1b += __shfl_xor(p1b, 32, 64);
    p0a += __shfl_xor(p0a, 16, 64); p1a += __shfl_xor(p1a, 16, 64);
    p0b += __shfl_xor(p0b, 16, 64); p1b += __shfl_xor(p1b, 16, 64);
    float w = (grp & 2) ? ((grp & 1) ? p1b : p0b) : ((grp & 1) ? p1a : p0a);
#pragma unroll
    for (int m = 8; m >= 1; m >>= 1) w += __shfl_xor(w, m, 64);
    // group leaders store: grp0->[2e], grp1->[2e+1], grp2->[2e+2], grp3->[2e+3]
    if ((lane & 15) == 0) {
      float val = w + bsel;
      size_t oi = (size_t)e * 2 + grp;
      if (usef) outEf[oi] = val;
      else outE[oi] = f2b(val);
    }
  }
}

extern "C" void kernel_launch(void* const* d_in, const int* in_sizes, int n_in,
                              void* d_out, int out_size, void* d_ws, size_t ws_size,
                              hipStream_t stream) {
  char* wp = (char*)d_ws;
  auto alloc = [&](size_t bytes) -> char* {
    char* p = wp; wp += (bytes + 255) & ~(size_t)255; return p;
  };
  int* flag       = (int*)alloc(256);
  u16* c_h        = (u16*)alloc((size_t)N_NODES * 128 * 2);
  u16* c_ef       = (u16*)alloc((size_t)N_EDGES * 6 * 2);
  static const int pidx[20] = {4,5,6,7,8, 9,10,11,12, 13,14,15,16,17,18, 19,20,21,22,23};
  static const int pn[20]   = {16384,128,32768,256,32768, 1280,5,5,5,
                               135168,256,256,256,512,2, 65536,256,32768,128,32768};
  u16* cp[20];
  for (int a = 0; a < 20; a++) cp[a] = (u16*)alloc((size_t)pn[a] * 2);

  u16* wt_encpool = (u16*)alloc(128 * 128 * 2);
  u16* wt_enc     = (u16*)alloc(256 * 256 * 2);
  u16* wt_decpool = (u16*)alloc(256 * 256 * 2);
  u16* wt_dec     = (u16*)alloc(128 * 512 * 2);
  u16* wt_UV      = (u16*)alloc(512 * 288 * 2);
  u16* b512       = (u16*)alloc(512 * 2);
  float2* Srow    = (float2*)alloc((size_t)N_NODES * 8);
  float* swsum_b  = (float*)alloc(64);
  u16* m_buf      = (u16*)alloc((size_t)N_NODES * 256 * 2);
  u16* aggb       = (u16*)alloc((size_t)N_NODES * 256 * 2);
  u16* UVbuf      = m_buf;  // m_buf+aggb contiguous => [N][512] during edge phase
  u16* h1b        = (u16*)alloc((size_t)N_NODES * 256 * 2);
  u16* smb32      = (u16*)alloc((size_t)N_NODES * 32 * 2);
  int* deg        = (int*)alloc((size_t)N_NODES * 4);
  int* off        = (int*)alloc((size_t)(N_NODES + 1) * 4);
  int* cursor     = (int*)alloc((size_t)N_NODES * 4);
  int* esrc       = (int*)alloc((size_t)N_EDGES * 4);

  const int* src = (const int*)d_in[2];
  const int* dst = (const int*)d_in[3];

  u16* outN = (u16*)d_out;
  u16* outE = outN + (size_t)N_NODES * 5;
  u16* outH = outN + 1110000;
  float* outNf = (float*)d_out;
  float* outEf = outNf + (size_t)N_NODES * 5;
  float* outHf = outNf + 1110000;

  // --- dtype sniff + input conversion ---
  sniff<<<1, 256, 0, stream>>>((const u16*)d_in[0], flag);
  conv_arr<<<15000, 256, 0, stream>>>(d_in[0], c_h, N_NODES * 128, flag);
  conv_arr<<<11250, 256, 0, stream>>>(d_in[1], c_ef, N_EDGES * 6, flag);
  ConvTab tab;
  int off_a = 0;
  for (int a = 0; a < 20; a++) {
    tab.e[a].s = d_in[pidx[a]]; tab.e[a].d = cp[a]; tab.e[a].n = pn[a]; tab.e[a].off = off_a;
    off_a += pn[a];
  }
  tab.total = off_a;
  conv_params<<<(off_a + 255) / 256, 256, 0, stream>>>(tab, flag);

  const u16 *enc_Wpool = cp[0], *enc_bpool = cp[1], *enc_Wself = cp[2], *enc_bself = cp[3],
            *enc_Wneigh = cp[4], *np_W = cp[5], *np_b = cp[6], *np_g = cp[7], *np_beta = cp[8],
            *ep_W1 = cp[9], *ep_b1 = cp[10], *ep_g = cp[11], *ep_beta = cp[12],
            *ep_W2 = cp[13], *ep_b2 = cp[14], *dec_Wpool = cp[15], *dec_bpool = cp[16],
            *dec_Wself = cp[17], *dec_bself = cp[18], *dec_Wneigh = cp[19];

  // --- CSR build (shared by both aggregations) ---
  hipMemsetAsync(deg, 0, (size_t)N_NODES * 4, stream);
  deg_count<<<1875, 256, 0, stream>>>(dst, deg, N_EDGES);
  scan_off<<<1, 256, 0, stream>>>(deg, off, N_NODES);
  hipMemcpyAsync(cursor, off, (size_t)N_NODES * 4, hipMemcpyDeviceToDevice, stream);
  fill_csr<<<1875, 256, 0, stream>>>(src, dst, cursor, esrc, N_EDGES);

  // --- weight prep ---
  transpose_k<<<64, 256, 0, stream>>>(enc_Wpool, wt_encpool, 128, 7, 128, 0);
  transpose_k<<<128, 256, 0, stream>>>(enc_Wself, wt_enc, 128, 8, 256, 0);
  transpose_k<<<128, 256, 0, stream>>>(enc_Wneigh, wt_enc, 128, 8, 256, 128);
  transpose_k<<<256, 256, 0, stream>>>(dec_Wpool, wt_decpool, 256, 8, 256, 0);
  transpose_k<<<128, 256, 0, stream>>>(dec_Wself, wt_dec, 256, 7, 512, 0);
  transpose_k<<<128, 256, 0, stream>>>(dec_Wneigh, wt_dec, 256, 7, 512, 256);
  hipMemsetAsync(wt_UV, 0, 512 * 288 * 2, stream);
  transpose_k<<<256, 256, 0, stream>>>(ep_W1, wt_UV, 256, 8, 288, 0);
  transpose_k<<<5, 256, 0, stream>>>(ep_W1 + 256 * 256, wt_UV, 5, 8, 288, 256);
  transpose_k<<<256, 256, 0, stream>>>(ep_W1 + 267 * 256, wt_UV + 256 * 288, 256, 8, 288, 0);
  transpose_k<<<5, 256, 0, stream>>>(ep_W1 + 523 * 256, wt_UV + 256 * 288, 5, 8, 288, 256);
  hipMemsetAsync(b512, 0, 512 * 2, stream);
  hipMemcpyAsync(b512, ep_b1, 256 * 2, hipMemcpyDeviceToDevice, stream);
  wefsum<<<1, 384, 0, stream>>>(ep_W1, swsum_b);

  // --- encoder ---
  gemm_mfma<<<dim3(235, 1), 256, 0, stream>>>(c_h, nullptr, 128, 0, wt_encpool,
                                              enc_bpool, 1, m_buf, nullptr, flag, N_NODES, 128);
  agg128<<<7500, 256, 0, stream>>>(m_buf, esrc, off, aggb);
  gemm_mfma<<<dim3(235, 2), 256, 0, stream>>>(c_h, aggb, 128, 128, wt_enc,
                                              enc_bself, 1, h1b, nullptr, flag, N_NODES, 256);
  // --- node head ---
  node_head<<<118, 256, 0, stream>>>(h1b, np_W, np_b, np_g, np_beta, outN, outNf, flag, smb32);
  // --- edge head: UV GEMM -> row sums -> pointwise ---
  gemm_mfma<<<dim3(235, 4), 256, 0, stream>>>(h1b, smb32, 256, 32, wt_UV,
                                              b512, 0, UVbuf, nullptr, flag, N_NODES, 512);
  rowsum_uv<<<7500, 256, 0, stream>>>(UVbuf, Srow);
  edge_pt<<<1875, 256, 0, stream>>>(UVbuf, Srow, swsum_b, c_ef, src, dst, ep_W1,
                                    ep_g, ep_beta, ep_W2, ep_b2, outE, outEf, flag);
  // --- decoder ---
  gemm_mfma<<<dim3(235, 2), 256, 0, stream>>>(h1b, nullptr, 256, 0, wt_decpool,
                                              dec_bpool, 1, m_buf, nullptr, flag, N_NODES, 256);
  agg256<<<7500, 256, 0, stream>>>(m_buf, esrc, off, aggb);
  gemm_mfma<<<dim3(235, 1), 256, 0, stream>>>(h1b, aggb, 256, 256, wt_dec,
                                              dec_bself, 1, outH, outHf, flag, N_NODES, 128);
}

// Round 8
// 497.872 us; speedup vs baseline: 1.3772x; 1.2112x over previous
//
#include <hip/hip_runtime.h>

typedef unsigned short u16;
typedef unsigned int u32;
typedef __bf16 bf16_t;
typedef bf16_t bf16x8 __attribute__((ext_vector_type(8)));
typedef float f32x4 __attribute__((ext_vector_type(4)));

#define N_NODES 30000
#define N_EDGES 480000

static __device__ __forceinline__ float b2f(u16 u) {
  return __uint_as_float(((u32)u) << 16);
}
static __device__ __forceinline__ float b2f_lo(u32 w) {
  return __uint_as_float(w << 16);
}
static __device__ __forceinline__ float b2f_hi(u32 w) {
  return __uint_as_float(w & 0xffff0000u);
}
static __device__ __forceinline__ u16 f2b(float f) {
  u32 x = __float_as_uint(f);
  u32 r = (x + 0x7fffu + ((x >> 16) & 1u)) >> 16;
  return (u16)r;
}

// ---------------- init: zero deg; block 0 sniffs dtype (bf16=0 / f32=1) ----------------
__global__ __launch_bounds__(256) void init_sniff_deg(const u16* __restrict__ h,
                                                      int* __restrict__ flag,
                                                      int* __restrict__ deg) {
  int i = blockIdx.x * 256 + threadIdx.x;
  if (i < N_NODES) deg[i] = 0;
  if (blockIdx.x == 0) {
    int t = threadIdx.x;
    int bad = 0;
#pragma unroll
    for (int j = 0; j < 4; j++) {
      u32 e = ((u32)h[t * 4 + j] >> 7) & 0xFFu;
      if (e >= 0x8Eu) bad = 1;  // impossible magnitude for N(0,1) bf16 data
    }
    int r = __syncthreads_or(bad);
    if (t == 0) *flag = r ? 1 : 0;
  }
}

// ---------------- vectorized convert (4 elems/thread) ----------------
__global__ __launch_bounds__(256) void conv_arr4(const void* __restrict__ src,
                                                 u16* __restrict__ dst, int n4,
                                                 const int* __restrict__ flag) {
  int i = blockIdx.x * 256 + threadIdx.x;
  if (i >= n4) return;
  if (*flag) {
    float4 f = ((const float4*)src)[i];
    uint2 o;
    o.x = (u32)f2b(f.x) | ((u32)f2b(f.y) << 16);
    o.y = (u32)f2b(f.z) | ((u32)f2b(f.w) << 16);
    ((uint2*)dst)[i] = o;
  } else {
    ((uint2*)dst)[i] = ((const uint2*)src)[i];
  }
}

struct ConvDesc { const void* s; u16* d; int n; int off; };
struct ConvTab { ConvDesc e[20]; int total; };

__global__ __launch_bounds__(256) void conv_params(ConvTab tab, const int* __restrict__ flag) {
  int i = blockIdx.x * 256 + threadIdx.x;
  if (i >= tab.total) return;
  int f = *flag;
#pragma unroll 1
  for (int a = 0; a < 20; a++) {
    int j = i - tab.e[a].off;
    if (j >= 0 && j < tab.e[a].n) {
      if (f) tab.e[a].d[j] = f2b(((const float*)tab.e[a].s)[j]);
      else tab.e[a].d[j] = ((const u16*)tab.e[a].s)[j];
      return;
    }
  }
}

// ---------------- CSR build ----------------
__global__ __launch_bounds__(256) void deg_count(const int* __restrict__ dst,
                                                 int* __restrict__ deg, int nE) {
  int e = blockIdx.x * 256 + threadIdx.x;
  if (e < nE) atomicAdd(&deg[dst[e]], 1);
}

__global__ __launch_bounds__(1024) void scan_off(const int* __restrict__ deg,
                                                 int* __restrict__ off,
                                                 int* __restrict__ cursor, int n) {
  __shared__ int carry;
  __shared__ int wsum[16];
  int t = threadIdx.x, lane = t & 63, wv = t >> 6;
  if (t == 0) { carry = 0; off[0] = 0; }
  __syncthreads();
  for (int base = 0; base < n; base += 1024) {
    int v = (base + t < n) ? deg[base + t] : 0;
    int x = v;
#pragma unroll
    for (int d = 1; d < 64; d <<= 1) {
      int y = __shfl_up(x, d, 64);
      if (lane >= d) x += y;
    }
    if (lane == 63) wsum[wv] = x;
    __syncthreads();
    int wadd = 0;
    for (int w = 0; w < wv; w++) wadd += wsum[w];
    int incl = x + wadd + carry;
    if (base + t < n) { off[base + t + 1] = incl; cursor[base + t] = incl - v; }
    __syncthreads();
    if (t == 1023) carry = incl;
    __syncthreads();
  }
}

__global__ __launch_bounds__(256) void fill_csr(const int* __restrict__ src,
                                                const int* __restrict__ dst,
                                                int* __restrict__ cursor,
                                                int* __restrict__ esrc, int nE) {
  int e = blockIdx.x * 256 + threadIdx.x;
  if (e >= nE) return;
  int p = atomicAdd(&cursor[dst[e]], 1);
  esrc[p] = src[e];
}

// ---------------- CSR max-aggregate (unsigned max == float max for bf16 >= 0) ----------------
__global__ __launch_bounds__(256) void agg128(const u16* __restrict__ m,
                                              const int* __restrict__ esrc,
                                              const int* __restrict__ off,
                                              u16* __restrict__ out) {
  int wv = threadIdx.x >> 6, lane = threadIdx.x & 63;
  int n = blockIdx.x * 4 + wv;
  if (n >= N_NODES) return;
  int s0 = off[n], s1 = off[n + 1];
  u32 a0 = 0, a1 = 0;
  int i = s0;
  for (; i + 3 < s1; i += 4) {
    int e0 = esrc[i], e1 = esrc[i + 1], e2 = esrc[i + 2], e3 = esrc[i + 3];
    u32 r0 = *(const u32*)(m + (size_t)e0 * 128 + lane * 2);
    u32 r1 = *(const u32*)(m + (size_t)e1 * 128 + lane * 2);
    u32 r2 = *(const u32*)(m + (size_t)e2 * 128 + lane * 2);
    u32 r3 = *(const u32*)(m + (size_t)e3 * 128 + lane * 2);
    a0 = max(a0, r0 & 0xffffu); a1 = max(a1, r0 >> 16);
    a0 = max(a0, r1 & 0xffffu); a1 = max(a1, r1 >> 16);
    a0 = max(a0, r2 & 0xffffu); a1 = max(a1, r2 >> 16);
    a0 = max(a0, r3 & 0xffffu); a1 = max(a1, r3 >> 16);
  }
  for (; i < s1; i++) {
    u32 ra = *(const u32*)(m + (size_t)esrc[i] * 128 + lane * 2);
    a0 = max(a0, ra & 0xffffu); a1 = max(a1, ra >> 16);
  }
  *(u32*)(out + (size_t)n * 128 + lane * 2) = a0 | (a1 << 16);
}

__global__ __launch_bounds__(256) void agg256(const u16* __restrict__ m,
                                              const int* __restrict__ esrc,
                                              const int* __restrict__ off,
                                              u16* __restrict__ out) {
  int wv = threadIdx.x >> 6, lane = threadIdx.x & 63;
  int n = blockIdx.x * 4 + wv;
  if (n >= N_NODES) return;
  int s0 = off[n], s1 = off[n + 1];
  u32 a0 = 0, a1 = 0, a2 = 0, a3 = 0;
  int i = s0;
  for (; i + 3 < s1; i += 4) {
    int e0 = esrc[i], e1 = esrc[i + 1], e2 = esrc[i + 2], e3 = esrc[i + 3];
    uint2 r0 = *(const uint2*)(m + (size_t)e0 * 256 + lane * 4);
    uint2 r1 = *(const uint2*)(m + (size_t)e1 * 256 + lane * 4);
    uint2 r2 = *(const uint2*)(m + (size_t)e2 * 256 + lane * 4);
    uint2 r3 = *(const uint2*)(m + (size_t)e3 * 256 + lane * 4);
    a0 = max(a0, r0.x & 0xffffu); a1 = max(a1, r0.x >> 16);
    a2 = max(a2, r0.y & 0xffffu); a3 = max(a3, r0.y >> 16);
    a0 = max(a0, r1.x & 0xffffu); a1 = max(a1, r1.x >> 16);
    a2 = max(a2, r1.y & 0xffffu); a3 = max(a3, r1.y >> 16);
    a0 = max(a0, r2.x & 0xffffu); a1 = max(a1, r2.x >> 16);
    a2 = max(a2, r2.y & 0xffffu); a3 = max(a3, r2.y >> 16);
    a0 = max(a0, r3.x & 0xffffu); a1 = max(a1, r3.x >> 16);
    a2 = max(a2, r3.y & 0xffffu); a3 = max(a3, r3.y >> 16);
  }
  for (; i < s1; i++) {
    uint2 ra = *(const uint2*)(m + (size_t)esrc[i] * 256 + lane * 4);
    a0 = max(a0, ra.x & 0xffffu); a1 = max(a1, ra.x >> 16);
    a2 = max(a2, ra.y & 0xffffu); a3 = max(a3, ra.y >> 16);
  }
  uint2 w;
  w.x = a0 | (a1 << 16);
  w.y = a2 | (a3 << 16);
  *(uint2*)(out + (size_t)n * 256 + lane * 4) = w;
}

// ---------------- fused weight prep: all transposes + UV build + b512 + wefsum ----------------
__global__ __launch_bounds__(256) void prep_weights(
    const u16* __restrict__ encWp, const u16* __restrict__ encWs, const u16* __restrict__ encWn,
    const u16* __restrict__ decWp, const u16* __restrict__ decWs, const u16* __restrict__ decWn,
    const u16* __restrict__ epW1, const u16* __restrict__ epb1,
    u16* __restrict__ wt_encpool, u16* __restrict__ wt_enc,
    u16* __restrict__ wt_decpool, u16* __restrict__ wt_dec,
    u16* __restrict__ wt_UV, u16* __restrict__ b512, float* __restrict__ swsum) {
  int b = blockIdx.x;
  const int t = threadIdx.x;
  if (b < 64) {   // enc_Wpool^T: [128n][128k]
    int idx = b * 256 + t; int k = idx >> 7, n = idx & 127;
    wt_encpool[n * 128 + k] = encWp[k * 128 + n]; return;
  }
  b -= 64;
  if (b < 128) {  // enc_Wself^T -> wt_enc[:, 0:128]
    int idx = b * 256 + t; int k = idx >> 8, n = idx & 255;
    wt_enc[n * 256 + k] = encWs[k * 256 + n]; return;
  }
  b -= 128;
  if (b < 128) {  // enc_Wneigh^T -> wt_enc[:, 128:256]
    int idx = b * 256 + t; int k = idx >> 8, n = idx & 255;
    wt_enc[n * 256 + 128 + k] = encWn[k * 256 + n]; return;
  }
  b -= 128;
  if (b < 256) {  // dec_Wpool^T: [256n][256k]
    int idx = b * 256 + t; int k = idx >> 8, n = idx & 255;
    wt_decpool[n * 256 + k] = decWp[k * 256 + n]; return;
  }
  b -= 256;
  if (b < 128) {  // dec_Wself^T -> wt_dec[:, 0:256]
    int idx = b * 256 + t; int k = idx >> 7, n = idx & 127;
    wt_dec[n * 512 + k] = decWs[k * 128 + n]; return;
  }
  b -= 128;
  if (b < 128) {  // dec_Wneigh^T -> wt_dec[:, 256:512]
    int idx = b * 256 + t; int k = idx >> 7, n = idx & 127;
    wt_dec[n * 512 + 256 + k] = decWn[k * 128 + n]; return;
  }
  b -= 128;
  if (b < 512) {  // wt_UV: U half rows base 0, V half rows base 267; kp<261 live, else 0
    int n = b, n2 = n & 255, base = (n >= 256) ? 267 : 0;
    for (int kp = t; kp < 288; kp += 256) {
      u16 v = (kp < 261) ? epW1[(size_t)(base + kp) * 256 + n2] : (u16)0;
      wt_UV[(size_t)n * 288 + kp] = v;
    }
    return;
  }
  b -= 512;
  if (b < 2) {    // b512 = [ep_b1 | zeros]
    int i = b * 256 + t;
    b512[i] = (i < 256) ? epb1[i] : (u16)0; return;
  }
  // wefsum: swsum[k] = sum_c W1[261+k][c], k<6 (8 groups of 32 lanes, guard)
  int k = t >> 5, l32 = t & 31;
  if (k < 6) {
    uint4 v = *(const uint4*)(epW1 + (size_t)(261 + k) * 256 + l32 * 8);
    float s = b2f_lo(v.x) + b2f_hi(v.x) + b2f_lo(v.y) + b2f_hi(v.y) +
              b2f_lo(v.z) + b2f_hi(v.z) + b2f_lo(v.w) + b2f_hi(v.w);
#pragma unroll
    for (int m = 1; m < 32; m <<= 1) s += __shfl_xor(s, m, 64);
    if (l32 == 0) swsum[k] = s;
  }
}

// ---------------- generic MFMA GEMM: C = act(concat(A0,A1) @ Bt^T + bias) ----------------
__global__ __launch_bounds__(256) void gemm_mfma(
    const u16* __restrict__ A0, const u16* __restrict__ A1, int K0, int K1,
    const u16* __restrict__ Bt, const u16* __restrict__ bias, int do_relu,
    u16* __restrict__ C, float* __restrict__ Cf, const int* __restrict__ flag,
    int M, int Nld) {
  __shared__ __align__(16) u16 As[128 * 40];
  __shared__ __align__(16) u16 Bs[128 * 40];
  const int t = threadIdx.x;
  const int lane = t & 63, wv = t >> 6;
  const int wm = wv & 1, wn = wv >> 1;
  const int r = lane & 15, q = lane >> 4;
  const int bm = blockIdx.x, bn = blockIdx.y;
  const int Ktot = K0 + K1;
  const bool usef = (Cf != nullptr) && (*flag != 0);

  f32x4 acc[4][4];
#pragma unroll
  for (int i = 0; i < 4; i++)
#pragma unroll
    for (int j = 0; j < 4; j++) acc[i][j] = (f32x4){0.f, 0.f, 0.f, 0.f};

  for (int kc = 0; kc < Ktot; kc += 32) {
#pragma unroll
    for (int h = 0; h < 2; h++) {
      int idx = t + h * 256;          // 0..511
      int rr = idx >> 2, qq = idx & 3;
      int rowg = bm * 128 + rr;
      uint4 av = make_uint4(0, 0, 0, 0);
      if (rowg < M) {
        const u16* p = (kc < K0) ? (A0 + (size_t)rowg * K0 + kc)
                                 : (A1 + (size_t)rowg * K1 + (kc - K0));
        av = *(const uint4*)(p + qq * 8);
      }
      *(uint4*)&As[rr * 40 + qq * 8] = av;
      int ng = bn * 128 + rr;
      uint4 bv = *(const uint4*)(Bt + (size_t)ng * Ktot + kc + qq * 8);
      *(uint4*)&Bs[rr * 40 + qq * 8] = bv;
    }
    __syncthreads();
    bf16x8 af[4], bfm[4];
#pragma unroll
    for (int mi = 0; mi < 4; mi++)
      af[mi] = *(const bf16x8*)&As[(wm * 64 + mi * 16 + r) * 40 + q * 8];
#pragma unroll
    for (int ni = 0; ni < 4; ni++)
      bfm[ni] = *(const bf16x8*)&Bs[(wn * 64 + ni * 16 + r) * 40 + q * 8];
#pragma unroll
    for (int mi = 0; mi < 4; mi++)
#pragma unroll
      for (int ni = 0; ni < 4; ni++)
        acc[mi][ni] = __builtin_amdgcn_mfma_f32_16x16x32_bf16(af[mi], bfm[ni], acc[mi][ni], 0, 0, 0);
    __syncthreads();
  }

  float bv[4];
#pragma unroll
  for (int ni = 0; ni < 4; ni++)
    bv[ni] = bias ? b2f(bias[bn * 128 + wn * 64 + ni * 16 + r]) : 0.f;
#pragma unroll
  for (int mi = 0; mi < 4; mi++) {
#pragma unroll
    for (int i = 0; i < 4; i++) {
      int rowg = bm * 128 + wm * 64 + mi * 16 + q * 4 + i;
      if (rowg >= M) continue;
#pragma unroll
      for (int ni = 0; ni < 4; ni++) {
        int colg = bn * 128 + wn * 64 + ni * 16 + r;
        float v = acc[mi][ni][i] + bv[ni];
        if (do_relu) v = v > 0.f ? v : 0.f;
        if (usef) Cf[(size_t)rowg * Nld + colg] = v;
        else C[(size_t)rowg * Nld + colg] = f2b(v);
      }
    }
  }
}

// ---------------- node head: node_pred = LN(h1@W + b), smb32 = [softmax | 0-pad] ----------------
__global__ __launch_bounds__(256) void node_head(
    const u16* __restrict__ h1, const u16* __restrict__ W, const u16* __restrict__ b,
    const u16* __restrict__ g, const u16* __restrict__ beta,
    u16* __restrict__ outN, float* __restrict__ outNf, const int* __restrict__ flag,
    u16* __restrict__ smOut) {
  __shared__ float Wl[256 * 5];
  __shared__ float bl[5], gl[5], betal[5];
  int t = threadIdx.x;
#pragma unroll
  for (int c = 0; c < 5; c++) Wl[t * 5 + c] = b2f(W[t * 5 + c]);
  if (t < 5) { bl[t] = b2f(b[t]); gl[t] = b2f(g[t]); betal[t] = b2f(beta[t]); }
  __syncthreads();
  int n = blockIdx.x * 256 + t;
  if (n >= N_NODES) return;
  const bool usef = (*flag != 0);
  float acc[5] = {0.f, 0.f, 0.f, 0.f, 0.f};
  const u16* hp = h1 + (size_t)n * 256;
  for (int k8 = 0; k8 < 32; k8++) {
    uint4 v = *(const uint4*)(hp + k8 * 8);
    u32 wds[4] = {v.x, v.y, v.z, v.w};
#pragma unroll
    for (int h = 0; h < 4; h++) {
      float x0 = b2f_lo(wds[h]), x1 = b2f_hi(wds[h]);
      int k = k8 * 8 + h * 2;
#pragma unroll
      for (int c = 0; c < 5; c++)
        acc[c] += x0 * Wl[k * 5 + c] + x1 * Wl[(k + 1) * 5 + c];
    }
  }
  float x[5], mu = 0.f;
#pragma unroll
  for (int c = 0; c < 5; c++) { x[c] = acc[c] + bl[c]; mu += x[c]; }
  mu *= 0.2f;
  float var = 0.f;
#pragma unroll
  for (int c = 0; c < 5; c++) { float d = x[c] - mu; var += d * d; }
  var *= 0.2f;
  float rstd = rsqrtf(fmaxf(var, 0.f) + 1e-5f);
  float v5[5], mx = -1e30f;
#pragma unroll
  for (int c = 0; c < 5; c++) {
    v5[c] = gl[c] * (x[c] - mu) * rstd + betal[c];
    if (usef) outNf[(size_t)n * 5 + c] = v5[c];
    else outN[(size_t)n * 5 + c] = f2b(v5[c]);
    mx = fmaxf(mx, v5[c]);
  }
  float s = 0.f, ex[5];
#pragma unroll
  for (int c = 0; c < 5; c++) { ex[c] = __expf(v5[c] - mx); s += ex[c]; }
  float inv = 1.f / s;
  u16 row[32];
#pragma unroll
  for (int c = 0; c < 5; c++) row[c] = f2b(ex[c] * inv);
#pragma unroll
  for (int c = 5; c < 32; c++) row[c] = 0;
#pragma unroll
  for (int c = 0; c < 4; c++)
    *(uint4*)(smOut + (size_t)n * 32 + c * 8) = *(const uint4*)&row[c * 8];
}

// ---------------- row sums of UV ----------------
__global__ __launch_bounds__(256) void rowsum_uv(const u16* __restrict__ UV,
                                                 float2* __restrict__ Srow) {
  int wv = threadIdx.x >> 6, lane = threadIdx.x & 63;
  int n = blockIdx.x * 4 + wv;
  if (n >= N_NODES) return;
  uint4 v = *(const uint4*)(UV + (size_t)n * 512 + lane * 8);
  float s = b2f_lo(v.x) + b2f_hi(v.x) + b2f_lo(v.y) + b2f_hi(v.y) +
            b2f_lo(v.z) + b2f_hi(v.z) + b2f_lo(v.w) + b2f_hi(v.w);
#pragma unroll
  for (int m = 1; m < 32; m <<= 1) s += __shfl_xor(s, m, 64);
  if (lane == 0) Srow[n].x = s;    // U half (lanes 0-31)
  if (lane == 32) Srow[n].y = s;   // V half (lanes 32-63)
}

// ---------------- edge pointwise v3: pair-per-iteration, reduced shuffle trees ----------------
__global__ __launch_bounds__(256) void edge_pt(
    const u16* __restrict__ UV, const float2* __restrict__ Srow,
    const float* __restrict__ swsum, const u16* __restrict__ ef,
    const int* __restrict__ src, const int* __restrict__ dst,
    const u16* __restrict__ w1raw,
    const u16* __restrict__ g, const u16* __restrict__ beta,
    const u16* __restrict__ w2, const u16* __restrict__ b2,
    u16* __restrict__ outE, float* __restrict__ outEf, const int* __restrict__ flag) {
  const int t = threadIdx.x;
  const int lane = t & 63, wv = t >> 6;
  const int c0 = lane * 4;
  const int grp = (lane >> 4) & 3;  // 16-lane group id
  float wef[6][4], gl[4], bl[4], w20[4], w21[4];
#pragma unroll
  for (int k = 0; k < 6; k++) {
    u32 wa = *(const u32*)(w1raw + (size_t)(261 + k) * 256 + c0);
    u32 wb = *(const u32*)(w1raw + (size_t)(261 + k) * 256 + c0 + 2);
    wef[k][0] = b2f_lo(wa); wef[k][1] = b2f_hi(wa);
    wef[k][2] = b2f_lo(wb); wef[k][3] = b2f_hi(wb);
  }
#pragma unroll
  for (int j = 0; j < 4; j++) {
    gl[j] = b2f(g[c0 + j]); bl[j] = b2f(beta[c0 + j]);
    w20[j] = b2f(w2[(c0 + j) * 2]); w21[j] = b2f(w2[(c0 + j) * 2 + 1]);
  }
  float sw[6];
#pragma unroll
  for (int k = 0; k < 6; k++) sw[k] = swsum[k];
  const float b20 = b2f(b2[0]), b21 = b2f(b2[1]);
  const float bsel = (grp & 1) ? b21 : b20;
  const bool usef = (*flag != 0);

  const int pbase = (blockIdx.x * 4 + wv) * 32;  // 1875*4*32 pairs = 240000
  int sa = src[pbase * 2], da = dst[pbase * 2];
  int sb = src[pbase * 2 + 1], db = dst[pbase * 2 + 1];
#pragma unroll 1
  for (int it = 0; it < 32; ++it) {
    const int e = (pbase + it) * 2;
    int sac = sa, dac = da, sbc = sb, dbc = db;
    if (it + 1 < 32) {
      sa = src[e + 2]; da = dst[e + 2]; sb = src[e + 3]; db = dst[e + 3];
    }
    uint2 ua = *(const uint2*)(UV + (size_t)sac * 512 + c0);
    uint2 va = *(const uint2*)(UV + (size_t)dac * 512 + 256 + c0);
    uint2 ub = *(const uint2*)(UV + (size_t)sbc * 512 + c0);
    uint2 vb = *(const uint2*)(UV + (size_t)dbc * 512 + 256 + c0);
    float2 sra = Srow[sac], srda = Srow[dac];
    float2 srb = Srow[sbc], srdb = Srow[dbc];
    const u32* efp = (const u32*)(ef + (size_t)e * 6);
    u32 f0 = efp[0], f1 = efp[1], f2 = efp[2], f3 = efp[3], f4 = efp[4], f5 = efp[5];
    float xa[6] = {b2f_lo(f0), b2f_hi(f0), b2f_lo(f1), b2f_hi(f1), b2f_lo(f2), b2f_hi(f2)};
    float xb[6] = {b2f_lo(f3), b2f_hi(f3), b2f_lo(f4), b2f_hi(f4), b2f_lo(f5), b2f_hi(f5)};

    float ma = sra.x + srda.y, mb = srb.x + srdb.y;
#pragma unroll
    for (int k = 0; k < 6; k++) { ma += xa[k] * sw[k]; mb += xb[k] * sw[k]; }
    ma *= (1.f / 256.f); mb *= (1.f / 256.f);

    float ya[4], yb[4];
    ya[0] = b2f_lo(ua.x) + b2f_lo(va.x); yb[0] = b2f_lo(ub.x) + b2f_lo(vb.x);
    ya[1] = b2f_hi(ua.x) + b2f_hi(va.x); yb[1] = b2f_hi(ub.x) + b2f_hi(vb.x);
    ya[2] = b2f_lo(ua.y) + b2f_lo(va.y); yb[2] = b2f_lo(ub.y) + b2f_lo(vb.y);
    ya[3] = b2f_hi(ua.y) + b2f_hi(va.y); yb[3] = b2f_hi(ub.y) + b2f_hi(vb.y);
#pragma unroll
    for (int k = 0; k < 6; k++)
#pragma unroll
      for (int j = 0; j < 4; j++) {
        ya[j] += xa[k] * wef[k][j];
        yb[j] += xb[k] * wef[k][j];
      }
    float pqa = ya[0] * ya[0] + ya[1] * ya[1] + ya[2] * ya[2] + ya[3] * ya[3];
    float pqb = yb[0] * yb[0] + yb[1] * yb[1] + yb[2] * yb[2] + yb[3] * yb[3];
    pqa += __shfl_xor(pqa, 32, 64);
    pqb += __shfl_xor(pqb, 32, 64);
    float z = (lane < 32) ? pqa : pqb;
#pragma unroll
    for (int m = 16; m >= 1; m >>= 1) z += __shfl_xor(z, m, 64);
    float zz = __shfl_xor(z, 32, 64);
    float pqa_t = (lane < 32) ? z : zz;
    float pqb_t = (lane < 32) ? zz : z;
    float rsa = rsqrtf(fmaxf(pqa_t * (1.f / 256.f) - ma * ma, 0.f) + 1e-5f);
    float rsb = rsqrtf(fmaxf(pqb_t * (1.f / 256.f) - mb * mb, 0.f) + 1e-5f);
    float p0a = 0.f, p1a = 0.f, p0b = 0.f, p1b = 0.f;
#pragma unroll
    for (int j = 0; j < 4; j++) {
      float na = fmaxf((ya[j] - ma) * rsa * gl[j] + bl[j], 0.f);
      float nb = fmaxf((yb[j] - mb) * rsb * gl[j] + bl[j], 0.f);
      p0a += na * w20[j]; p1a += na * w21[j];
      p0b += nb * w20[j]; p1b += nb * w21[j];
    }
    p0a += __shfl_xor(p0a, 32, 64); p1a += __shfl_xor(p1a, 32, 64);
    p0b += __shfl_xor(p0b, 32, 64); p1b += __shfl_xor(p1b, 32, 64);
    p0a += __shfl_xor(p0a, 16, 64); p1a += __shfl_xor(p1a, 16, 64);
    p0b += __shfl_xor(p0b, 16, 64); p1b += __shfl_xor(p1b, 16, 64);
    float w = (grp & 2) ? ((grp & 1) ? p1b : p0b) : ((grp & 1) ? p1a : p0a);
#pragma unroll
    for (int m = 8; m >= 1; m >>= 1) w += __shfl_xor(w, m, 64);
    if ((lane & 15) == 0) {
      float val = w + bsel;
      size_t oi = (size_t)e * 2 + grp;
      if (usef) outEf[oi] = val;
      else outE[oi] = f2b(val);
    }
  }
}

extern "C" void kernel_launch(void* const* d_in, const int* in_sizes, int n_in,
                              void* d_out, int out_size, void* d_ws, size_t ws_size,
                              hipStream_t stream) {
  char* wp = (char*)d_ws;
  auto alloc = [&](size_t bytes) -> char* {
    char* p = wp; wp += (bytes + 255) & ~(size_t)255; return p;
  };
  int* flag       = (int*)alloc(256);
  u16* c_h        = (u16*)alloc((size_t)N_NODES * 128 * 2);
  u16* c_ef       = (u16*)alloc((size_t)N_EDGES * 6 * 2);
  static const int pidx[20] = {4,5,6,7,8, 9,10,11,12, 13,14,15,16,17,18, 19,20,21,22,23};
  static const int pn[20]   = {16384,128,32768,256,32768, 1280,5,5,5,
                               135168,256,256,256,512,2, 65536,256,32768,128,32768};
  u16* cp[20];
  for (int a = 0; a < 20; a++) cp[a] = (u16*)alloc((size_t)pn[a] * 2);

  u16* wt_encpool = (u16*)alloc(128 * 128 * 2);
  u16* wt_enc     = (u16*)alloc(256 * 256 * 2);
  u16* wt_decpool = (u16*)alloc(256 * 256 * 2);
  u16* wt_dec     = (u16*)alloc(128 * 512 * 2);
  u16* wt_UV      = (u16*)alloc(512 * 288 * 2);
  u16* b512       = (u16*)alloc(512 * 2);
  float2* Srow    = (float2*)alloc((size_t)N_NODES * 8);
  float* swsum_b  = (float*)alloc(64);
  u16* m_buf      = (u16*)alloc((size_t)N_NODES * 256 * 2);
  u16* aggb       = (u16*)alloc((size_t)N_NODES * 256 * 2);
  u16* UVbuf      = m_buf;  // m_buf+aggb contiguous => [N][512] during edge phase
  u16* h1b        = (u16*)alloc((size_t)N_NODES * 256 * 2);
  u16* smb32      = (u16*)alloc((size_t)N_NODES * 32 * 2);
  int* deg        = (int*)alloc((size_t)N_NODES * 4);
  int* off        = (int*)alloc((size_t)(N_NODES + 1) * 4);
  int* cursor     = (int*)alloc((size_t)N_NODES * 4);
  int* esrc       = (int*)alloc((size_t)N_EDGES * 4);

  const int* src = (const int*)d_in[2];
  const int* dst = (const int*)d_in[3];

  u16* outN = (u16*)d_out;
  u16* outE = outN + (size_t)N_NODES * 5;
  u16* outH = outN + 1110000;
  float* outNf = (float*)d_out;
  float* outEf = outNf + (size_t)N_NODES * 5;
  float* outHf = outNf + 1110000;

  // --- init (deg zero + dtype sniff) ---
  init_sniff_deg<<<118, 256, 0, stream>>>((const u16*)d_in[0], flag, deg);
  // --- input conversion (vectorized x4) ---
  conv_arr4<<<3750, 256, 0, stream>>>(d_in[0], c_h, 960000, flag);
  conv_arr4<<<2813, 256, 0, stream>>>(d_in[1], c_ef, 720000, flag);
  ConvTab tab;
  int off_a = 0;
  for (int a = 0; a < 20; a++) {
    tab.e[a].s = d_in[pidx[a]]; tab.e[a].d = cp[a]; tab.e[a].n = pn[a]; tab.e[a].off = off_a;
    off_a += pn[a];
  }
  tab.total = off_a;
  conv_params<<<(off_a + 255) / 256, 256, 0, stream>>>(tab, flag);

  const u16 *enc_Wpool = cp[0], *enc_bpool = cp[1], *enc_Wself = cp[2], *enc_bself = cp[3],
            *enc_Wneigh = cp[4], *np_W = cp[5], *np_b = cp[6], *np_g = cp[7], *np_beta = cp[8],
            *ep_W1 = cp[9], *ep_b1 = cp[10], *ep_g = cp[11], *ep_beta = cp[12],
            *ep_W2 = cp[13], *ep_b2 = cp[14], *dec_Wpool = cp[15], *dec_bpool = cp[16],
            *dec_Wself = cp[17], *dec_bself = cp[18], *dec_Wneigh = cp[19];

  // --- CSR build (cursor written by scan_off; no memcpy) ---
  deg_count<<<1875, 256, 0, stream>>>(dst, deg, N_EDGES);
  scan_off<<<1, 1024, 0, stream>>>(deg, off, cursor, N_NODES);
  fill_csr<<<1875, 256, 0, stream>>>(src, dst, cursor, esrc, N_EDGES);

  // --- fused weight prep (replaces 10 transposes + 2 memsets + memcpy + wefsum) ---
  prep_weights<<<1347, 256, 0, stream>>>(enc_Wpool, enc_Wself, enc_Wneigh,
                                         dec_Wpool, dec_Wself, dec_Wneigh,
                                         ep_W1, ep_b1,
                                         wt_encpool, wt_enc, wt_decpool, wt_dec,
                                         wt_UV, b512, swsum_b);

  // --- encoder ---
  gemm_mfma<<<dim3(235, 1), 256, 0, stream>>>(c_h, nullptr, 128, 0, wt_encpool,
                                              enc_bpool, 1, m_buf, nullptr, flag, N_NODES, 128);
  agg128<<<7500, 256, 0, stream>>>(m_buf, esrc, off, aggb);
  gemm_mfma<<<dim3(235, 2), 256, 0, stream>>>(c_h, aggb, 128, 128, wt_enc,
                                              enc_bself, 1, h1b, nullptr, flag, N_NODES, 256);
  // --- node head ---
  node_head<<<118, 256, 0, stream>>>(h1b, np_W, np_b, np_g, np_beta, outN, outNf, flag, smb32);
  // --- edge head: UV GEMM -> row sums -> pointwise ---
  gemm_mfma<<<dim3(235, 4), 256, 0, stream>>>(h1b, smb32, 256, 32, wt_UV,
                                              b512, 0, UVbuf, nullptr, flag, N_NODES, 512);
  rowsum_uv<<<7500, 256, 0, stream>>>(UVbuf, Srow);
  edge_pt<<<1875, 256, 0, stream>>>(UVbuf, Srow, swsum_b, c_ef, src, dst, ep_W1,
                                    ep_g, ep_beta, ep_W2, ep_b2, outE, outEf, flag);
  // --- decoder ---
  gemm_mfma<<<dim3(235, 2), 256, 0, stream>>>(h1b, nullptr, 256, 0, wt_decpool,
                                              dec_bpool, 1, m_buf, nullptr, flag, N_NODES, 256);
  agg256<<<7500, 256, 0, stream>>>(m_buf, esrc, off, aggb);
  gemm_mfma<<<dim3(235, 1), 256, 0, stream>>>(h1b, aggb, 256, 256, wt_dec,
                                              dec_bself, 1, outH, outHf, flag, N_NODES, 128);
}

// Round 9
// 473.997 us; speedup vs baseline: 1.4466x; 1.0504x over previous
//
#include <hip/hip_runtime.h>

typedef unsigned short u16;
typedef unsigned int u32;
typedef __bf16 bf16_t;
typedef bf16_t bf16x8 __attribute__((ext_vector_type(8)));
typedef float f32x4 __attribute__((ext_vector_type(4)));

#define N_NODES 30000
#define N_EDGES 480000

static __device__ __forceinline__ float b2f(u16 u) {
  return __uint_as_float(((u32)u) << 16);
}
static __device__ __forceinline__ float b2f_lo(u32 w) {
  return __uint_as_float(w << 16);
}
static __device__ __forceinline__ float b2f_hi(u32 w) {
  return __uint_as_float(w & 0xffff0000u);
}
static __device__ __forceinline__ u16 f2b(float f) {
  u32 x = __float_as_uint(f);
  u32 r = (x + 0x7fffu + ((x >> 16) & 1u)) >> 16;
  return (u16)r;
}

// ---------------- init: zero deg; block 0 sniffs dtype (bf16=0 / f32=1) ----------------
__global__ __launch_bounds__(256) void init_sniff_deg(const u16* __restrict__ h,
                                                      int* __restrict__ flag,
                                                      int* __restrict__ deg) {
  int i = blockIdx.x * 256 + threadIdx.x;
  if (i < N_NODES) deg[i] = 0;
  if (blockIdx.x == 0) {
    int t = threadIdx.x;
    int bad = 0;
#pragma unroll
    for (int j = 0; j < 4; j++) {
      u32 e = ((u32)h[t * 4 + j] >> 7) & 0xFFu;
      if (e >= 0x8Eu) bad = 1;  // impossible magnitude for N(0,1) bf16 data
    }
    int r = __syncthreads_or(bad);
    if (t == 0) *flag = r ? 1 : 0;
  }
}

struct ConvDesc { const void* s; u16* d; int n; int off; };
struct ConvTab { ConvDesc e[20]; int total; };

// ---------------- fused front-end: deg_count | conv h | conv ef | conv params ----------------
// blocks [0,1875): deg_count; [1875,5625): h conv x4; [5625,8438): ef conv x4; rest: params.
__global__ __launch_bounds__(256) void conv_all(
    const int* __restrict__ dstE, int* __restrict__ deg,
    const void* __restrict__ hsrc, u16* __restrict__ c_h,
    const void* __restrict__ efsrc, u16* __restrict__ c_ef,
    ConvTab tab, const int* __restrict__ flag) {
  int b = blockIdx.x;
  const int t = threadIdx.x;
  if (b < 1875) {
    int e = b * 256 + t;
    if (e < N_EDGES) atomicAdd(&deg[dstE[e]], 1);
    return;
  }
  b -= 1875;
  const int f = *flag;
  if (b < 3750) {  // h: 960000 uint2-groups
    int i = b * 256 + t;
    if (f) {
      float4 v = ((const float4*)hsrc)[i];
      uint2 o;
      o.x = (u32)f2b(v.x) | ((u32)f2b(v.y) << 16);
      o.y = (u32)f2b(v.z) | ((u32)f2b(v.w) << 16);
      ((uint2*)c_h)[i] = o;
    } else {
      ((uint2*)c_h)[i] = ((const uint2*)hsrc)[i];
    }
    return;
  }
  b -= 3750;
  if (b < 2813) {  // ef: 720000 4-elem groups
    int i = b * 256 + t;
    if (i < 720000) {
      if (f) {
        float4 v = ((const float4*)efsrc)[i];
        uint2 o;
        o.x = (u32)f2b(v.x) | ((u32)f2b(v.y) << 16);
        o.y = (u32)f2b(v.z) | ((u32)f2b(v.w) << 16);
        ((uint2*)c_ef)[i] = o;
      } else {
        ((uint2*)c_ef)[i] = ((const uint2*)efsrc)[i];
      }
    }
    return;
  }
  b -= 2813;
  int i = b * 256 + t;
  if (i >= tab.total) return;
#pragma unroll 1
  for (int a = 0; a < 20; a++) {
    int j = i - tab.e[a].off;
    if (j >= 0 && j < tab.e[a].n) {
      if (f) tab.e[a].d[j] = f2b(((const float*)tab.e[a].s)[j]);
      else tab.e[a].d[j] = ((const u16*)tab.e[a].s)[j];
      return;
    }
  }
}

__global__ __launch_bounds__(1024) void scan_off(const int* __restrict__ deg,
                                                 int* __restrict__ off,
                                                 int* __restrict__ cursor, int n) {
  __shared__ int carry;
  __shared__ int wsum[16];
  int t = threadIdx.x, lane = t & 63, wv = t >> 6;
  if (t == 0) { carry = 0; off[0] = 0; }
  __syncthreads();
  for (int base = 0; base < n; base += 1024) {
    int v = (base + t < n) ? deg[base + t] : 0;
    int x = v;
#pragma unroll
    for (int d = 1; d < 64; d <<= 1) {
      int y = __shfl_up(x, d, 64);
      if (lane >= d) x += y;
    }
    if (lane == 63) wsum[wv] = x;
    __syncthreads();
    int wadd = 0;
    for (int w = 0; w < wv; w++) wadd += wsum[w];
    int incl = x + wadd + carry;
    if (base + t < n) { off[base + t + 1] = incl; cursor[base + t] = incl - v; }
    __syncthreads();
    if (t == 1023) carry = incl;
    __syncthreads();
  }
}

__global__ __launch_bounds__(256) void fill_csr(const int* __restrict__ src,
                                                const int* __restrict__ dst,
                                                int* __restrict__ cursor,
                                                int* __restrict__ esrc, int nE) {
  int e = blockIdx.x * 256 + threadIdx.x;
  if (e >= nE) return;
  int p = atomicAdd(&cursor[dst[e]], 1);
  esrc[p] = src[e];
}

// ---------------- CSR max-aggregate (unsigned max == float max for bf16 >= 0) ----------------
// 4 nodes per wave; 16 lanes x uint4 per row (128 cols).
__global__ __launch_bounds__(256) void agg128(const u16* __restrict__ m,
                                              const int* __restrict__ esrc,
                                              const int* __restrict__ off,
                                              u16* __restrict__ out) {
  int wv = threadIdx.x >> 6, lane = threadIdx.x & 63;
  int qd = lane >> 4, l = lane & 15;
  int n = blockIdx.x * 16 + wv * 4 + qd;
  if (n >= N_NODES) return;
  int i = off[n], s1 = off[n + 1];
  u32 a0 = 0, a1 = 0, a2 = 0, a3 = 0, a4 = 0, a5 = 0, a6 = 0, a7 = 0;
  for (; i + 1 < s1; i += 2) {
    int e0 = esrc[i], e1 = esrc[i + 1];
    uint4 r0 = *(const uint4*)(m + (size_t)e0 * 128 + l * 8);
    uint4 r1 = *(const uint4*)(m + (size_t)e1 * 128 + l * 8);
    a0 = max(a0, r0.x & 0xffffu); a1 = max(a1, r0.x >> 16);
    a2 = max(a2, r0.y & 0xffffu); a3 = max(a3, r0.y >> 16);
    a4 = max(a4, r0.z & 0xffffu); a5 = max(a5, r0.z >> 16);
    a6 = max(a6, r0.w & 0xffffu); a7 = max(a7, r0.w >> 16);
    a0 = max(a0, r1.x & 0xffffu); a1 = max(a1, r1.x >> 16);
    a2 = max(a2, r1.y & 0xffffu); a3 = max(a3, r1.y >> 16);
    a4 = max(a4, r1.z & 0xffffu); a5 = max(a5, r1.z >> 16);
    a6 = max(a6, r1.w & 0xffffu); a7 = max(a7, r1.w >> 16);
  }
  if (i < s1) {
    uint4 r0 = *(const uint4*)(m + (size_t)esrc[i] * 128 + l * 8);
    a0 = max(a0, r0.x & 0xffffu); a1 = max(a1, r0.x >> 16);
    a2 = max(a2, r0.y & 0xffffu); a3 = max(a3, r0.y >> 16);
    a4 = max(a4, r0.z & 0xffffu); a5 = max(a5, r0.z >> 16);
    a6 = max(a6, r0.w & 0xffffu); a7 = max(a7, r0.w >> 16);
  }
  uint4 w;
  w.x = a0 | (a1 << 16); w.y = a2 | (a3 << 16);
  w.z = a4 | (a5 << 16); w.w = a6 | (a7 << 16);
  *(uint4*)(out + (size_t)n * 128 + l * 8) = w;
}

// 2 nodes per wave; 32 lanes x uint4 per row (256 cols).
__global__ __launch_bounds__(256) void agg256(const u16* __restrict__ m,
                                              const int* __restrict__ esrc,
                                              const int* __restrict__ off,
                                              u16* __restrict__ out) {
  int wv = threadIdx.x >> 6, lane = threadIdx.x & 63;
  int half = lane >> 5, l = lane & 31;
  int n = blockIdx.x * 8 + wv * 2 + half;
  if (n >= N_NODES) return;
  int i = off[n], s1 = off[n + 1];
  u32 a0 = 0, a1 = 0, a2 = 0, a3 = 0, a4 = 0, a5 = 0, a6 = 0, a7 = 0;
  for (; i + 1 < s1; i += 2) {
    int e0 = esrc[i], e1 = esrc[i + 1];
    uint4 r0 = *(const uint4*)(m + (size_t)e0 * 256 + l * 8);
    uint4 r1 = *(const uint4*)(m + (size_t)e1 * 256 + l * 8);
    a0 = max(a0, r0.x & 0xffffu); a1 = max(a1, r0.x >> 16);
    a2 = max(a2, r0.y & 0xffffu); a3 = max(a3, r0.y >> 16);
    a4 = max(a4, r0.z & 0xffffu); a5 = max(a5, r0.z >> 16);
    a6 = max(a6, r0.w & 0xffffu); a7 = max(a7, r0.w >> 16);
    a0 = max(a0, r1.x & 0xffffu); a1 = max(a1, r1.x >> 16);
    a2 = max(a2, r1.y & 0xffffu); a3 = max(a3, r1.y >> 16);
    a4 = max(a4, r1.z & 0xffffu); a5 = max(a5, r1.z >> 16);
    a6 = max(a6, r1.w & 0xffffu); a7 = max(a7, r1.w >> 16);
  }
  if (i < s1) {
    uint4 r0 = *(const uint4*)(m + (size_t)esrc[i] * 256 + l * 8);
    a0 = max(a0, r0.x & 0xffffu); a1 = max(a1, r0.x >> 16);
    a2 = max(a2, r0.y & 0xffffu); a3 = max(a3, r0.y >> 16);
    a4 = max(a4, r0.z & 0xffffu); a5 = max(a5, r0.z >> 16);
    a6 = max(a6, r0.w & 0xffffu); a7 = max(a7, r0.w >> 16);
  }
  uint4 w;
  w.x = a0 | (a1 << 16); w.y = a2 | (a3 << 16);
  w.z = a4 | (a5 << 16); w.w = a6 | (a7 << 16);
  *(uint4*)(out + (size_t)n * 256 + l * 8) = w;
}

// ---------------- fused weight prep: all transposes + UV build + b512 + wefsum ----------------
__global__ __launch_bounds__(256) void prep_weights(
    const u16* __restrict__ encWp, const u16* __restrict__ encWs, const u16* __restrict__ encWn,
    const u16* __restrict__ decWp, const u16* __restrict__ decWs, const u16* __restrict__ decWn,
    const u16* __restrict__ epW1, const u16* __restrict__ epb1,
    u16* __restrict__ wt_encpool, u16* __restrict__ wt_enc,
    u16* __restrict__ wt_decpool, u16* __restrict__ wt_dec,
    u16* __restrict__ wt_UV, u16* __restrict__ b512, float* __restrict__ swsum) {
  int b = blockIdx.x;
  const int t = threadIdx.x;
  if (b < 64) {
    int idx = b * 256 + t; int k = idx >> 7, n = idx & 127;
    wt_encpool[n * 128 + k] = encWp[k * 128 + n]; return;
  }
  b -= 64;
  if (b < 128) {
    int idx = b * 256 + t; int k = idx >> 8, n = idx & 255;
    wt_enc[n * 256 + k] = encWs[k * 256 + n]; return;
  }
  b -= 128;
  if (b < 128) {
    int idx = b * 256 + t; int k = idx >> 8, n = idx & 255;
    wt_enc[n * 256 + 128 + k] = encWn[k * 256 + n]; return;
  }
  b -= 128;
  if (b < 256) {
    int idx = b * 256 + t; int k = idx >> 8, n = idx & 255;
    wt_decpool[n * 256 + k] = decWp[k * 256 + n]; return;
  }
  b -= 256;
  if (b < 128) {
    int idx = b * 256 + t; int k = idx >> 7, n = idx & 127;
    wt_dec[n * 512 + k] = decWs[k * 128 + n]; return;
  }
  b -= 128;
  if (b < 128) {
    int idx = b * 256 + t; int k = idx >> 7, n = idx & 127;
    wt_dec[n * 512 + 256 + k] = decWn[k * 128 + n]; return;
  }
  b -= 128;
  if (b < 512) {
    int n = b, n2 = n & 255, base = (n >= 256) ? 267 : 0;
    for (int kp = t; kp < 288; kp += 256) {
      u16 v = (kp < 261) ? epW1[(size_t)(base + kp) * 256 + n2] : (u16)0;
      wt_UV[(size_t)n * 288 + kp] = v;
    }
    return;
  }
  b -= 512;
  if (b < 2) {
    int i = b * 256 + t;
    b512[i] = (i < 256) ? epb1[i] : (u16)0; return;
  }
  int k = t >> 5, l32 = t & 31;
  if (k < 6) {
    uint4 v = *(const uint4*)(epW1 + (size_t)(261 + k) * 256 + l32 * 8);
    float s = b2f_lo(v.x) + b2f_hi(v.x) + b2f_lo(v.y) + b2f_hi(v.y) +
              b2f_lo(v.z) + b2f_hi(v.z) + b2f_lo(v.w) + b2f_hi(v.w);
#pragma unroll
    for (int m = 1; m < 32; m <<= 1) s += __shfl_xor(s, m, 64);
    if (l32 == 0) swsum[k] = s;
  }
}

// ---------------- generic MFMA GEMM: C = act(concat(A0,A1) @ Bt^T + bias) ----------------
__global__ __launch_bounds__(256) void gemm_mfma(
    const u16* __restrict__ A0, const u16* __restrict__ A1, int K0, int K1,
    const u16* __restrict__ Bt, const u16* __restrict__ bias, int do_relu,
    u16* __restrict__ C, float* __restrict__ Cf, const int* __restrict__ flag,
    int M, int Nld) {
  __shared__ __align__(16) u16 As[128 * 40];
  __shared__ __align__(16) u16 Bs[128 * 40];
  const int t = threadIdx.x;
  const int lane = t & 63, wv = t >> 6;
  const int wm = wv & 1, wn = wv >> 1;
  const int r = lane & 15, q = lane >> 4;
  const int bm = blockIdx.x, bn = blockIdx.y;
  const int Ktot = K0 + K1;
  const bool usef = (Cf != nullptr) && (*flag != 0);

  f32x4 acc[4][4];
#pragma unroll
  for (int i = 0; i < 4; i++)
#pragma unroll
    for (int j = 0; j < 4; j++) acc[i][j] = (f32x4){0.f, 0.f, 0.f, 0.f};

  for (int kc = 0; kc < Ktot; kc += 32) {
#pragma unroll
    for (int h = 0; h < 2; h++) {
      int idx = t + h * 256;          // 0..511
      int rr = idx >> 2, qq = idx & 3;
      int rowg = bm * 128 + rr;
      uint4 av = make_uint4(0, 0, 0, 0);
      if (rowg < M) {
        const u16* p = (kc < K0) ? (A0 + (size_t)rowg * K0 + kc)
                                 : (A1 + (size_t)rowg * K1 + (kc - K0));
        av = *(const uint4*)(p + qq * 8);
      }
      *(uint4*)&As[rr * 40 + qq * 8] = av;
      int ng = bn * 128 + rr;
      uint4 bv = *(const uint4*)(Bt + (size_t)ng * Ktot + kc + qq * 8);
      *(uint4*)&Bs[rr * 40 + qq * 8] = bv;
    }
    __syncthreads();
    bf16x8 af[4], bfm[4];
#pragma unroll
    for (int mi = 0; mi < 4; mi++)
      af[mi] = *(const bf16x8*)&As[(wm * 64 + mi * 16 + r) * 40 + q * 8];
#pragma unroll
    for (int ni = 0; ni < 4; ni++)
      bfm[ni] = *(const bf16x8*)&Bs[(wn * 64 + ni * 16 + r) * 40 + q * 8];
#pragma unroll
    for (int mi = 0; mi < 4; mi++)
#pragma unroll
      for (int ni = 0; ni < 4; ni++)
        acc[mi][ni] = __builtin_amdgcn_mfma_f32_16x16x32_bf16(af[mi], bfm[ni], acc[mi][ni], 0, 0, 0);
    __syncthreads();
  }

  float bv[4];
#pragma unroll
  for (int ni = 0; ni < 4; ni++)
    bv[ni] = bias ? b2f(bias[bn * 128 + wn * 64 + ni * 16 + r]) : 0.f;
#pragma unroll
  for (int mi = 0; mi < 4; mi++) {
#pragma unroll
    for (int i = 0; i < 4; i++) {
      int rowg = bm * 128 + wm * 64 + mi * 16 + q * 4 + i;
      if (rowg >= M) continue;
#pragma unroll
      for (int ni = 0; ni < 4; ni++) {
        int colg = bn * 128 + wn * 64 + ni * 16 + r;
        float v = acc[mi][ni][i] + bv[ni];
        if (do_relu) v = v > 0.f ? v : 0.f;
        if (usef) Cf[(size_t)rowg * Nld + colg] = v;
        else C[(size_t)rowg * Nld + colg] = f2b(v);
      }
    }
  }
}

// ---------------- node head: node_pred = LN(h1@W + b), smb32 = [softmax | 0-pad] ----------------
__global__ __launch_bounds__(256) void node_head(
    const u16* __restrict__ h1, const u16* __restrict__ W, const u16* __restrict__ b,
    const u16* __restrict__ g, const u16* __restrict__ beta,
    u16* __restrict__ outN, float* __restrict__ outNf, const int* __restrict__ flag,
    u16* __restrict__ smOut) {
  __shared__ float Wl[256 * 5];
  __shared__ float bl[5], gl[5], betal[5];
  int t = threadIdx.x;
#pragma unroll
  for (int c = 0; c < 5; c++) Wl[t * 5 + c] = b2f(W[t * 5 + c]);
  if (t < 5) { bl[t] = b2f(b[t]); gl[t] = b2f(g[t]); betal[t] = b2f(beta[t]); }
  __syncthreads();
  int n = blockIdx.x * 256 + t;
  if (n >= N_NODES) return;
  const bool usef = (*flag != 0);
  float acc[5] = {0.f, 0.f, 0.f, 0.f, 0.f};
  const u16* hp = h1 + (size_t)n * 256;
  for (int k8 = 0; k8 < 32; k8++) {
    uint4 v = *(const uint4*)(hp + k8 * 8);
    u32 wds[4] = {v.x, v.y, v.z, v.w};
#pragma unroll
    for (int h = 0; h < 4; h++) {
      float x0 = b2f_lo(wds[h]), x1 = b2f_hi(wds[h]);
      int k = k8 * 8 + h * 2;
#pragma unroll
      for (int c = 0; c < 5; c++)
        acc[c] += x0 * Wl[k * 5 + c] + x1 * Wl[(k + 1) * 5 + c];
    }
  }
  float x[5], mu = 0.f;
#pragma unroll
  for (int c = 0; c < 5; c++) { x[c] = acc[c] + bl[c]; mu += x[c]; }
  mu *= 0.2f;
  float var = 0.f;
#pragma unroll
  for (int c = 0; c < 5; c++) { float d = x[c] - mu; var += d * d; }
  var *= 0.2f;
  float rstd = rsqrtf(fmaxf(var, 0.f) + 1e-5f);
  float v5[5], mx = -1e30f;
#pragma unroll
  for (int c = 0; c < 5; c++) {
    v5[c] = gl[c] * (x[c] - mu) * rstd + betal[c];
    if (usef) outNf[(size_t)n * 5 + c] = v5[c];
    else outN[(size_t)n * 5 + c] = f2b(v5[c]);
    mx = fmaxf(mx, v5[c]);
  }
  float s = 0.f, ex[5];
#pragma unroll
  for (int c = 0; c < 5; c++) { ex[c] = __expf(v5[c] - mx); s += ex[c]; }
  float inv = 1.f / s;
  u16 row[32];
#pragma unroll
  for (int c = 0; c < 5; c++) row[c] = f2b(ex[c] * inv);
#pragma unroll
  for (int c = 5; c < 32; c++) row[c] = 0;
#pragma unroll
  for (int c = 0; c < 4; c++)
    *(uint4*)(smOut + (size_t)n * 32 + c * 8) = *(const uint4*)&row[c * 8];
}

// ---------------- row sums of UV ----------------
__global__ __launch_bounds__(256) void rowsum_uv(const u16* __restrict__ UV,
                                                 float2* __restrict__ Srow) {
  int wv = threadIdx.x >> 6, lane = threadIdx.x & 63;
  int n = blockIdx.x * 4 + wv;
  if (n >= N_NODES) return;
  uint4 v = *(const uint4*)(UV + (size_t)n * 512 + lane * 8);
  float s = b2f_lo(v.x) + b2f_hi(v.x) + b2f_lo(v.y) + b2f_hi(v.y) +
            b2f_lo(v.z) + b2f_hi(v.z) + b2f_lo(v.w) + b2f_hi(v.w);
#pragma unroll
  for (int m = 1; m < 32; m <<= 1) s += __shfl_xor(s, m, 64);
  if (lane == 0) Srow[n].x = s;    // U half (lanes 0-31)
  if (lane == 32) Srow[n].y = s;   // V half (lanes 32-63)
}

// ---------------- edge pointwise v3: pair-per-iteration, reduced shuffle trees ----------------
__global__ __launch_bounds__(256) void edge_pt(
    const u16* __restrict__ UV, const float2* __restrict__ Srow,
    const float* __restrict__ swsum, const u16* __restrict__ ef,
    const int* __restrict__ src, const int* __restrict__ dst,
    const u16* __restrict__ w1raw,
    const u16* __restrict__ g, const u16* __restrict__ beta,
    const u16* __restrict__ w2, const u16* __restrict__ b2,
    u16* __restrict__ outE, float* __restrict__ outEf, const int* __restrict__ flag) {
  const int t = threadIdx.x;
  const int lane = t & 63, wv = t >> 6;
  const int c0 = lane * 4;
  const int grp = (lane >> 4) & 3;  // 16-lane group id
  float wef[6][4], gl[4], bl[4], w20[4], w21[4];
#pragma unroll
  for (int k = 0; k < 6; k++) {
    u32 wa = *(const u32*)(w1raw + (size_t)(261 + k) * 256 + c0);
    u32 wb = *(const u32*)(w1raw + (size_t)(261 + k) * 256 + c0 + 2);
    wef[k][0] = b2f_lo(wa); wef[k][1] = b2f_hi(wa);
    wef[k][2] = b2f_lo(wb); wef[k][3] = b2f_hi(wb);
  }
#pragma unroll
  for (int j = 0; j < 4; j++) {
    gl[j] = b2f(g[c0 + j]); bl[j] = b2f(beta[c0 + j]);
    w20[j] = b2f(w2[(c0 + j) * 2]); w21[j] = b2f(w2[(c0 + j) * 2 + 1]);
  }
  float sw[6];
#pragma unroll
  for (int k = 0; k < 6; k++) sw[k] = swsum[k];
  const float b20 = b2f(b2[0]), b21 = b2f(b2[1]);
  const float bsel = (grp & 1) ? b21 : b20;
  const bool usef = (*flag != 0);

  const int pbase = (blockIdx.x * 4 + wv) * 16;  // 3750*4*16 pairs = 240000
  int sa = src[pbase * 2], da = dst[pbase * 2];
  int sb = src[pbase * 2 + 1], db = dst[pbase * 2 + 1];
#pragma unroll 1
  for (int it = 0; it < 16; ++it) {
    const int e = (pbase + it) * 2;
    int sac = sa, dac = da, sbc = sb, dbc = db;
    if (it + 1 < 16) {
      sa = src[e + 2]; da = dst[e + 2]; sb = src[e + 3]; db = dst[e + 3];
    }
    uint2 ua = *(const uint2*)(UV + (size_t)sac * 512 + c0);
    uint2 va = *(const uint2*)(UV + (size_t)dac * 512 + 256 + c0);
    uint2 ub = *(const uint2*)(UV + (size_t)sbc * 512 + c0);
    uint2 vb = *(const uint2*)(UV + (size_t)dbc * 512 + 256 + c0);
    float2 sra = Srow[sac], srda = Srow[dac];
    float2 srb = Srow[sbc], srdb = Srow[dbc];
    const u32* efp = (const u32*)(ef + (size_t)e * 6);
    u32 f0 = efp[0], f1 = efp[1], f2 = efp[2], f3 = efp[3], f4 = efp[4], f5 = efp[5];
    float xa[6] = {b2f_lo(f0), b2f_hi(f0), b2f_lo(f1), b2f_hi(f1), b2f_lo(f2), b2f_hi(f2)};
    float xb[6] = {b2f_lo(f3), b2f_hi(f3), b2f_lo(f4), b2f_hi(f4), b2f_lo(f5), b2f_hi(f5)};

    float ma = sra.x + srda.y, mb = srb.x + srdb.y;
#pragma unroll
    for (int k = 0; k < 6; k++) { ma += xa[k] * sw[k]; mb += xb[k] * sw[k]; }
    ma *= (1.f / 256.f); mb *= (1.f / 256.f);

    float ya[4], yb[4];
    ya[0] = b2f_lo(ua.x) + b2f_lo(va.x); yb[0] = b2f_lo(ub.x) + b2f_lo(vb.x);
    ya[1] = b2f_hi(ua.x) + b2f_hi(va.x); yb[1] = b2f_hi(ub.x) + b2f_hi(vb.x);
    ya[2] = b2f_lo(ua.y) + b2f_lo(va.y); yb[2] = b2f_lo(ub.y) + b2f_lo(vb.y);
    ya[3] = b2f_hi(ua.y) + b2f_hi(va.y); yb[3] = b2f_hi(ub.y) + b2f_hi(vb.y);
#pragma unroll
    for (int k = 0; k < 6; k++)
#pragma unroll
      for (int j = 0; j < 4; j++) {
        ya[j] += xa[k] * wef[k][j];
        yb[j] += xb[k] * wef[k][j];
      }
    float pqa = ya[0] * ya[0] + ya[1] * ya[1] + ya[2] * ya[2] + ya[3] * ya[3];
    float pqb = yb[0] * yb[0] + yb[1] * yb[1] + yb[2] * yb[2] + yb[3] * yb[3];
    pqa += __shfl_xor(pqa, 32, 64);
    pqb += __shfl_xor(pqb, 32, 64);
    float z = (lane < 32) ? pqa : pqb;
#pragma unroll
    for (int m = 16; m >= 1; m >>= 1) z += __shfl_xor(z, m, 64);
    float zz = __shfl_xor(z, 32, 64);
    float pqa_t = (lane < 32) ? z : zz;
    float pqb_t = (lane < 32) ? zz : z;
    float rsa = rsqrtf(fmaxf(pqa_t * (1.f / 256.f) - ma * ma, 0.f) + 1e-5f);
    float rsb = rsqrtf(fmaxf(pqb_t * (1.f / 256.f) - mb * mb, 0.f) + 1e-5f);
    float p0a = 0.f, p1a = 0.f, p0b = 0.f, p1b = 0.f;
#pragma unroll
    for (int j = 0; j < 4; j++) {
      float na = fmaxf((ya[j] - ma) * rsa * gl[j] + bl[j], 0.f);
      float nb = fmaxf((yb[j] - mb) * rsb * gl[j] + bl[j], 0.f);
      p0a += na * w20[j]; p1a += na * w21[j];
      p0b += nb * w20[j]; p1b += nb * w21[j];
    }
    p0a += __shfl_xor(p0a, 32, 64); p1a += __shfl_xor(p1a, 32, 64);
    p0b += __shfl_xor(p0b, 32, 64); p1b += __shfl_xor(p1b, 32, 64);
    p0a += __shfl_xor(p0a, 16, 64); p1a += __shfl_xor(p1a, 16, 64);
    p0b += __shfl_xor(p0b, 16, 64); p1b += __shfl_xor(p1b, 16, 64);
    float w = (grp & 2) ? ((grp & 1) ? p1b : p0b) : ((grp & 1) ? p1a : p0a);
#pragma unroll
    for (int m = 8; m >= 1; m >>= 1) w += __shfl_xor(w, m, 64);
    if ((lane & 15) == 0) {
      float val = w + bsel;
      size_t oi = (size_t)e * 2 + grp;
      if (usef) outEf[oi] = val;
      else outE[oi] = f2b(val);
    }
  }
}

extern "C" void kernel_launch(void* const* d_in, const int* in_sizes, int n_in,
                              void* d_out, int out_size, void* d_ws, size_t ws_size,
                              hipStream_t stream) {
  char* wp = (char*)d_ws;
  auto alloc = [&](size_t bytes) -> char* {
    char* p = wp; wp += (bytes + 255) & ~(size_t)255; return p;
  };
  int* flag       = (int*)alloc(256);
  u16* c_h        = (u16*)alloc((size_t)N_NODES * 128 * 2);
  u16* c_ef       = (u16*)alloc((size_t)N_EDGES * 6 * 2);
  static const int pidx[20] = {4,5,6,7,8, 9,10,11,12, 13,14,15,16,17,18, 19,20,21,22,23};
  static const int pn[20]   = {16384,128,32768,256,32768, 1280,5,5,5,
                               135168,256,256,256,512,2, 65536,256,32768,128,32768};
  u16* cp[20];
  for (int a = 0; a < 20; a++) cp[a] = (u16*)alloc((size_t)pn[a] * 2);

  u16* wt_encpool = (u16*)alloc(128 * 128 * 2);
  u16* wt_enc     = (u16*)alloc(256 * 256 * 2);
  u16* wt_decpool = (u16*)alloc(256 * 256 * 2);
  u16* wt_dec     = (u16*)alloc(128 * 512 * 2);
  u16* wt_UV      = (u16*)alloc(512 * 288 * 2);
  u16* b512       = (u16*)alloc(512 * 2);
  float2* Srow    = (float2*)alloc((size_t)N_NODES * 8);
  float* swsum_b  = (float*)alloc(64);
  u16* m_buf      = (u16*)alloc((size_t)N_NODES * 256 * 2);
  u16* aggb       = (u16*)alloc((size_t)N_NODES * 256 * 2);
  u16* UVbuf      = m_buf;  // m_buf+aggb contiguous => [N][512] during edge phase
  u16* h1b        = (u16*)alloc((size_t)N_NODES * 256 * 2);
  u16* smb32      = (u16*)alloc((size_t)N_NODES * 32 * 2);
  int* deg        = (int*)alloc((size_t)N_NODES * 4);
  int* off        = (int*)alloc((size_t)(N_NODES + 1) * 4);
  int* cursor     = (int*)alloc((size_t)N_NODES * 4);
  int* esrc       = (int*)alloc((size_t)N_EDGES * 4);

  const int* src = (const int*)d_in[2];
  const int* dst = (const int*)d_in[3];

  u16* outN = (u16*)d_out;
  u16* outE = outN + (size_t)N_NODES * 5;
  u16* outH = outN + 1110000;
  float* outNf = (float*)d_out;
  float* outEf = outNf + (size_t)N_NODES * 5;
  float* outHf = outNf + 1110000;

  // --- init (deg zero + dtype sniff) ---
  init_sniff_deg<<<118, 256, 0, stream>>>((const u16*)d_in[0], flag, deg);
  // --- fused front-end: deg_count + all conversions ---
  ConvTab tab;
  int off_a = 0;
  for (int a = 0; a < 20; a++) {
    tab.e[a].s = d_in[pidx[a]]; tab.e[a].d = cp[a]; tab.e[a].n = pn[a]; tab.e[a].off = off_a;
    off_a += pn[a];
  }
  tab.total = off_a;
  int conv_blocks = 1875 + 3750 + 2813 + (off_a + 255) / 256;
  conv_all<<<conv_blocks, 256, 0, stream>>>(dst, deg, d_in[0], c_h, d_in[1], c_ef, tab, flag);

  const u16 *enc_Wpool = cp[0], *enc_bpool = cp[1], *enc_Wself = cp[2], *enc_bself = cp[3],
            *enc_Wneigh = cp[4], *np_W = cp[5], *np_b = cp[6], *np_g = cp[7], *np_beta = cp[8],
            *ep_W1 = cp[9], *ep_b1 = cp[10], *ep_g = cp[11], *ep_beta = cp[12],
            *ep_W2 = cp[13], *ep_b2 = cp[14], *dec_Wpool = cp[15], *dec_bpool = cp[16],
            *dec_Wself = cp[17], *dec_bself = cp[18], *dec_Wneigh = cp[19];

  // --- CSR build ---
  scan_off<<<1, 1024, 0, stream>>>(deg, off, cursor, N_NODES);
  fill_csr<<<1875, 256, 0, stream>>>(src, dst, cursor, esrc, N_EDGES);

  // --- fused weight prep ---
  prep_weights<<<1347, 256, 0, stream>>>(enc_Wpool, enc_Wself, enc_Wneigh,
                                         dec_Wpool, dec_Wself, dec_Wneigh,
                                         ep_W1, ep_b1,
                                         wt_encpool, wt_enc, wt_decpool, wt_dec,
                                         wt_UV, b512, swsum_b);

  // --- encoder ---
  gemm_mfma<<<dim3(235, 1), 256, 0, stream>>>(c_h, nullptr, 128, 0, wt_encpool,
                                              enc_bpool, 1, m_buf, nullptr, flag, N_NODES, 128);
  agg128<<<1875, 256, 0, stream>>>(m_buf, esrc, off, aggb);
  gemm_mfma<<<dim3(235, 2), 256, 0, stream>>>(c_h, aggb, 128, 128, wt_enc,
                                              enc_bself, 1, h1b, nullptr, flag, N_NODES, 256);
  // --- node head ---
  node_head<<<118, 256, 0, stream>>>(h1b, np_W, np_b, np_g, np_beta, outN, outNf, flag, smb32);
  // --- edge head: UV GEMM -> row sums -> pointwise ---
  gemm_mfma<<<dim3(235, 4), 256, 0, stream>>>(h1b, smb32, 256, 32, wt_UV,
                                              b512, 0, UVbuf, nullptr, flag, N_NODES, 512);
  rowsum_uv<<<7500, 256, 0, stream>>>(UVbuf, Srow);
  edge_pt<<<3750, 256, 0, stream>>>(UVbuf, Srow, swsum_b, c_ef, src, dst, ep_W1,
                                    ep_g, ep_beta, ep_W2, ep_b2, outE, outEf, flag);
  // --- decoder ---
  gemm_mfma<<<dim3(235, 2), 256, 0, stream>>>(h1b, nullptr, 256, 0, wt_decpool,
                                              dec_bpool, 1, m_buf, nullptr, flag, N_NODES, 256);
  agg256<<<3750, 256, 0, stream>>>(m_buf, esrc, off, aggb);
  gemm_mfma<<<dim3(235, 1), 256, 0, stream>>>(h1b, aggb, 256, 256, wt_dec,
                                              dec_bself, 1, outH, outHf, flag, N_NODES, 128);
}